// Round 2
// baseline (564.608 us; speedup 1.0000x reference)
//
#include <hip/hip_runtime.h>
#include <math.h>

#define N_NODES 50000
#define N_EDGES 800000
#define ET (N_EDGES + N_NODES)   // edges + self loops
#define NEG_SLOPE 0.2f

#define SCAN_CHUNK 1024
#define SCAN_NB ((N_NODES + SCAN_CHUNK - 1) / SCAN_CHUNK)  // 49

__device__ __forceinline__ unsigned short f2bf(float f) {
    union { float f; unsigned u; } v; v.f = f;
    unsigned r = v.u + 0x7FFF + ((v.u >> 16) & 1);  // RNE
    return (unsigned short)(r >> 16);
}
__device__ __forceinline__ float bf2f(unsigned short s) {
    union { unsigned u; float f; } v; v.u = ((unsigned)s) << 16;
    return v.f;
}

// ---------------- CSR build ----------------

__global__ __launch_bounds__(256) void k_hist(const int* __restrict__ ei, int* __restrict__ deg) {
    int e = blockIdx.x * 256 + threadIdx.x;
    if (e >= ET) return;
    int v = (e < N_EDGES) ? ei[N_EDGES + e] : (e - N_EDGES);
    if (v >= 0 && v < N_NODES) atomicAdd(&deg[v], 1);
}

__global__ __launch_bounds__(256) void k_scan_reduce(const int* __restrict__ deg, int* __restrict__ bsum) {
    __shared__ int red[256];
    int b = blockIdx.x, tid = threadIdx.x;
    int s = 0;
    for (int i = tid; i < SCAN_CHUNK; i += 256) {
        int idx = b * SCAN_CHUNK + i;
        if (idx < N_NODES) s += deg[idx];
    }
    red[tid] = s;
    __syncthreads();
    for (int st = 128; st > 0; st >>= 1) {
        if (tid < st) red[tid] += red[tid + st];
        __syncthreads();
    }
    if (tid == 0) bsum[b] = red[0];
}

__global__ __launch_bounds__(64) void k_scan_top(const int* __restrict__ bsum, int* __restrict__ boff) {
    int lane = threadIdx.x;  // 64 threads, SCAN_NB <= 64
    int v = (lane < SCAN_NB) ? bsum[lane] : 0;
    int incl = v;
    for (int o = 1; o < 64; o <<= 1) {
        int t = __shfl_up(incl, o);
        if (lane >= o) incl += t;
    }
    boff[lane] = incl - v;
}

__global__ __launch_bounds__(256) void k_scan_chunk(const int* __restrict__ deg, const int* __restrict__ boff,
                                                   int* __restrict__ off) {
    __shared__ int wsum[4];
    int b = blockIdx.x, tid = threadIdx.x;
    int lane = tid & 63, wid = tid >> 6;
    int base = b * SCAN_CHUNK + tid * 4;
    int d[4];
#pragma unroll
    for (int j = 0; j < 4; ++j) d[j] = (base + j < N_NODES) ? deg[base + j] : 0;
    int tsum = d[0] + d[1] + d[2] + d[3];
    int incl = tsum;
    for (int o = 1; o < 64; o <<= 1) {
        int t = __shfl_up(incl, o);
        if (lane >= o) incl += t;
    }
    int wexcl = incl - tsum;
    if (lane == 63) wsum[wid] = incl;
    __syncthreads();
    int wbase = 0;
    for (int w = 0; w < wid; ++w) wbase += wsum[w];
    int run = boff[b] + wbase + wexcl;
#pragma unroll
    for (int j = 0; j < 4; ++j) {
        if (base + j < N_NODES) off[base + j] = run;
        run += d[j];
    }
    if (b == 0 && tid == 0) off[N_NODES] = ET;
}

__global__ __launch_bounds__(256) void k_scatter(const int* __restrict__ ei, const int* __restrict__ off,
                                                 int* __restrict__ cur, int* __restrict__ esrc) {
    int e = blockIdx.x * 256 + threadIdx.x;
    if (e >= ET) return;
    int u, v;
    if (e < N_EDGES) { u = ei[e]; v = ei[N_EDGES + e]; } else { u = e - N_EDGES; v = u; }
    if (v < 0 || v >= N_NODES) return;
    int p = off[v] + atomicAdd(&cur[v], 1);
    esrc[p] = u;
}

// ---------------- GEMM1: h1 = x @ W1  (50000x256 @ 256x256, fp32 in, bf16 out) ----------------
// 64x64 tile per block, BK=16, 256 threads, 4x4 microtile/thread.

__global__ __launch_bounds__(256) void k_gemm1(const float* __restrict__ X, const float* __restrict__ W,
                                               unsigned short* __restrict__ H) {
    __shared__ float AsT[16][68];
    __shared__ float Bs[16][64];
    int tid = threadIdx.x;
    int row0 = blockIdx.x * 64;
    int col0 = blockIdx.y * 64;
    int tx = tid & 15, ty = tid >> 4;
    int ar = tid >> 2;
    int ak = (tid & 3) * 4;
    int bk = tid >> 4;
    int bc = (tid & 15) * 4;
    float acc[4][4] = {};
    for (int k0 = 0; k0 < 256; k0 += 16) {
        float4 av = make_float4(0.f, 0.f, 0.f, 0.f);
        if (row0 + ar < N_NODES) av = *(const float4*)(X + (size_t)(row0 + ar) * 256 + k0 + ak);
        AsT[ak + 0][ar] = av.x; AsT[ak + 1][ar] = av.y; AsT[ak + 2][ar] = av.z; AsT[ak + 3][ar] = av.w;
        *(float4*)&Bs[bk][bc] = *(const float4*)(W + (size_t)(k0 + bk) * 256 + col0 + bc);
        __syncthreads();
#pragma unroll
        for (int k = 0; k < 16; ++k) {
            float4 avv = *(const float4*)&AsT[k][ty * 4];
            float4 bvv = *(const float4*)&Bs[k][tx * 4];
            float aa[4] = {avv.x, avv.y, avv.z, avv.w};
            float bb[4] = {bvv.x, bvv.y, bvv.z, bvv.w};
#pragma unroll
            for (int j = 0; j < 4; ++j)
#pragma unroll
                for (int i = 0; i < 4; ++i) acc[j][i] = fmaf(aa[j], bb[i], acc[j][i]);
        }
        __syncthreads();
    }
#pragma unroll
    for (int j = 0; j < 4; ++j) {
        int row = row0 + ty * 4 + j;
        if (row < N_NODES) {
            ushort4 o;
            o.x = f2bf(acc[j][0]); o.y = f2bf(acc[j][1]);
            o.z = f2bf(acc[j][2]); o.w = f2bf(acc[j][3]);
            *(ushort4*)(H + (size_t)row * 256 + col0 + tx * 4) = o;
        }
    }
}

// ---------------- Layer-1 attention logits (reads bf16 h1) ----------------

__global__ __launch_bounds__(256) void k_logits1(const unsigned short* __restrict__ H,
                                                 const float* __restrict__ a_src,
                                                 const float* __restrict__ a_dst, float* __restrict__ als,
                                                 float* __restrict__ ald) {
    int wid = (blockIdx.x * 256 + threadIdx.x) >> 6;
    int lane = threadIdx.x & 63;
    if (wid >= N_NODES) return;
    ushort4 hv = *(const ushort4*)(H + (size_t)wid * 256 + lane * 4);
    float hx = bf2f(hv.x), hy = bf2f(hv.y), hz = bf2f(hv.z), hw = bf2f(hv.w);
    float4 as = *(const float4*)(a_src + lane * 4);
    float4 ad = *(const float4*)(a_dst + lane * 4);
    float ps = hx * as.x + hy * as.y + hz * as.z + hw * as.w;
    float pd = hx * ad.x + hy * ad.y + hz * ad.z + hw * ad.w;
#pragma unroll
    for (int m = 8; m >= 1; m >>= 1) { ps += __shfl_xor(ps, m); pd += __shfl_xor(pd, m); }
    if ((lane & 15) == 0) {
        als[wid * 4 + (lane >> 4)] = ps;
        ald[wid * 4 + (lane >> 4)] = pd;
    }
}

// ---------------- Fused: layer-1 aggregation + bias + ELU + GEMM2 + layer-2 logits ----------------
// 4 waves/block, one node per wave; N=50000 divisible by 4 -> no bounds checks, all
// threads reach __syncthreads. W2 (256x32 fp32, 32KB) + per-wave h2 row (4x256, 4KB) in LDS.

__global__ __launch_bounds__(256) void k_agg1g2(const unsigned short* __restrict__ H1,
                                                const float* __restrict__ als, const float* __restrict__ ald_,
                                                const int* __restrict__ off, const int* __restrict__ esrc,
                                                const float* __restrict__ b1, const float* __restrict__ W2,
                                                const float* __restrict__ as2, const float* __restrict__ ad2,
                                                float* __restrict__ G, float* __restrict__ als2,
                                                float* __restrict__ ald2) {
    __shared__ float Ws[256 * 32];
    __shared__ float h2buf[4][256];
    int tid = threadIdx.x;
    for (int i = tid; i < 256 * 32; i += 256) Ws[i] = W2[i];
    int wv = tid >> 6, lane = tid & 63;
    int node = blockIdx.x * 4 + wv;   // always < N_NODES (12500*4 == 50000)
    int head = lane >> 4;
    float ald = ald_[node * 4 + head];
    int pstart = off[node], pend = off[node + 1];
    float m = -INFINITY, l = 0.f;
    float ax = 0.f, ay = 0.f, az = 0.f, aw = 0.f;
    const ushort4* H4 = (const ushort4*)H1;
    for (int p = pstart; p < pend; ++p) {
        int u = esrc[p];
        float e = als[u * 4 + head] + ald;
        e = e > 0.f ? e : NEG_SLOPE * e;
        float nm = fmaxf(m, e);
        float sc = __expf(m - nm);
        float pw = __expf(e - nm);
        l = l * sc + pw;
        m = nm;
        ushort4 hv = H4[(size_t)u * 64 + lane];
        ax = ax * sc + pw * bf2f(hv.x);
        ay = ay * sc + pw * bf2f(hv.y);
        az = az * sc + pw * bf2f(hv.z);
        aw = aw * sc + pw * bf2f(hv.w);
    }
    float inv = 1.f / l;
    int c = lane * 4;
    float4 bb = *(const float4*)(b1 + c);
    float o0 = ax * inv + bb.x, o1 = ay * inv + bb.y, o2 = az * inv + bb.z, o3 = aw * inv + bb.w;
    o0 = o0 > 0.f ? o0 : expm1f(o0);
    o1 = o1 > 0.f ? o1 : expm1f(o1);
    o2 = o2 > 0.f ? o2 : expm1f(o2);
    o3 = o3 > 0.f ? o3 : expm1f(o3);
    *(float4*)&h2buf[wv][c] = make_float4(o0, o1, o2, o3);
    __syncthreads();   // covers both W2 staging and h2buf writes
    int col = lane & 31, half = lane >> 5;
    const float* hrow = h2buf[wv];
    float sum = 0.f;
    int j0 = half * 128;
#pragma unroll 8
    for (int j = j0; j < j0 + 128; ++j) sum = fmaf(hrow[j], Ws[j * 32 + col], sum);
    float g = sum + __shfl_xor(sum, 32);
    if (half == 0) G[(size_t)node * 32 + col] = g;
    float ps = g * as2[col];
    float pd = g * ad2[col];
#pragma unroll
    for (int msk = 16; msk >= 1; msk >>= 1) { ps += __shfl_xor(ps, msk); pd += __shfl_xor(pd, msk); }
    if (lane == 0) { als2[node] = ps; ald2[node] = pd; }
}

// ---------------- Layer-2 aggregation + bias + log_softmax ----------------

__global__ __launch_bounds__(256) void k_agg2(const float* __restrict__ G, const float* __restrict__ als2,
                                              const float* __restrict__ ald2_, const int* __restrict__ off,
                                              const int* __restrict__ esrc, const float* __restrict__ b2,
                                              float* __restrict__ out) {
    int gid = blockIdx.x * 256 + threadIdx.x;
    int node = gid >> 5;
    int col = gid & 31;
    if (node >= N_NODES) return;
    float ald = ald2_[node];
    int pstart = off[node], pend = off[node + 1];
    float m = -INFINITY, l = 0.f, acc = 0.f;
    for (int p = pstart; p < pend; ++p) {
        int u = esrc[p];
        float e = als2[u] + ald;
        e = e > 0.f ? e : NEG_SLOPE * e;
        float nm = fmaxf(m, e);
        float sc = __expf(m - nm);
        float pw = __expf(e - nm);
        l = l * sc + pw;
        m = nm;
        acc = acc * sc + pw * G[(size_t)u * 32 + col];
    }
    float o = acc / l + b2[col];
    float mm = o;
#pragma unroll
    for (int msk = 16; msk >= 1; msk >>= 1) mm = fmaxf(mm, __shfl_xor(mm, msk));
    float ex = __expf(o - mm);
    float s = ex;
#pragma unroll
    for (int msk = 16; msk >= 1; msk >>= 1) s += __shfl_xor(s, msk);
    out[(size_t)node * 32 + col] = o - mm - logf(s);
}

// ---------------- launch ----------------

extern "C" void kernel_launch(void* const* d_in, const int* in_sizes, int n_in,
                              void* d_out, int out_size, void* d_ws, size_t ws_size,
                              hipStream_t stream) {
    const float* x   = (const float*)d_in[0];
    const int*   ei  = (const int*)d_in[1];
    const float* W1  = (const float*)d_in[2];
    const float* as1 = (const float*)d_in[3];
    const float* ad1 = (const float*)d_in[4];
    const float* b1  = (const float*)d_in[5];
    const float* W2  = (const float*)d_in[6];
    const float* as2 = (const float*)d_in[7];
    const float* ad2 = (const float*)d_in[8];
    const float* b2  = (const float*)d_in[9];
    float* out = (float*)d_out;

    char* p = (char*)d_ws;
    auto alloc = [&](size_t bytes) {
        char* r = p;
        p += (bytes + 255) & ~(size_t)255;
        return r;
    };
    // total workspace: ~38.2 MB (was ~115 MB in round 1 -> suspected d_ws overflow
    // corrupting the harness's pristine input copies; keep footprint small)
    unsigned short* h1 = (unsigned short*)alloc((size_t)N_NODES * 256 * 2);  // 25.6 MB bf16
    float* g    = (float*)alloc((size_t)N_NODES * 32 * 4);                   // 6.4 MB
    float* als1 = (float*)alloc((size_t)N_NODES * 4 * 4);
    float* ald1 = (float*)alloc((size_t)N_NODES * 4 * 4);
    float* als2 = (float*)alloc((size_t)N_NODES * 4);
    float* ald2 = (float*)alloc((size_t)N_NODES * 4);
    int* deg  = (int*)alloc((size_t)N_NODES * 4);
    int* cur  = (int*)alloc((size_t)N_NODES * 4);
    int* off  = (int*)alloc((size_t)(N_NODES + 1) * 4);
    int* bsum = (int*)alloc(64 * 4);
    int* boff = (int*)alloc(64 * 4);
    int* esrc = (int*)alloc((size_t)ET * 4);                                 // 3.4 MB

    hipMemsetAsync(deg, 0, (size_t)N_NODES * 4, stream);
    hipMemsetAsync(cur, 0, (size_t)N_NODES * 4, stream);

    k_hist<<<(ET + 255) / 256, 256, 0, stream>>>(ei, deg);
    k_scan_reduce<<<SCAN_NB, 256, 0, stream>>>(deg, bsum);
    k_scan_top<<<1, 64, 0, stream>>>(bsum, boff);
    k_scan_chunk<<<SCAN_NB, 256, 0, stream>>>(deg, boff, off);
    k_scatter<<<(ET + 255) / 256, 256, 0, stream>>>(ei, off, cur, esrc);

    k_gemm1<<<dim3((N_NODES + 63) / 64, 4), 256, 0, stream>>>(x, W1, h1);
    k_logits1<<<(N_NODES + 3) / 4, 256, 0, stream>>>(h1, as1, ad1, als1, ald1);
    k_agg1g2<<<N_NODES / 4, 256, 0, stream>>>(h1, als1, ald1, off, esrc, b1, W2, as2, ad2,
                                              g, als2, ald2);
    k_agg2<<<(N_NODES + 7) / 8, 256, 0, stream>>>(g, als2, ald2, off, esrc, b2, out);
}

// Round 3
// 420.796 us; speedup vs baseline: 1.3418x; 1.3418x over previous
//
#include <hip/hip_runtime.h>
#include <math.h>

#define N_NODES 50000
#define N_EDGES 800000
#define ET (N_EDGES + N_NODES)   // edges + self loops
#define NEG_SLOPE 0.2f

#define SCAN_CHUNK 1024
#define SCAN_NB ((N_NODES + SCAN_CHUNK - 1) / SCAN_CHUNK)  // 49

__device__ __forceinline__ unsigned short f2bf(float f) {
    union { float f; unsigned u; } v; v.f = f;
    unsigned r = v.u + 0x7FFF + ((v.u >> 16) & 1);  // RNE
    return (unsigned short)(r >> 16);
}
__device__ __forceinline__ float bf2f(unsigned short s) {
    union { unsigned u; float f; } v; v.u = ((unsigned)s) << 16;
    return v.f;
}

// ---------------- CSR build ----------------

__global__ __launch_bounds__(256) void k_hist(const int* __restrict__ ei, int* __restrict__ deg) {
    int e = blockIdx.x * 256 + threadIdx.x;
    if (e >= ET) return;
    int v = (e < N_EDGES) ? ei[N_EDGES + e] : (e - N_EDGES);
    if (v >= 0 && v < N_NODES) atomicAdd(&deg[v], 1);
}

__global__ __launch_bounds__(256) void k_scan_reduce(const int* __restrict__ deg, int* __restrict__ bsum) {
    __shared__ int red[256];
    int b = blockIdx.x, tid = threadIdx.x;
    int s = 0;
    for (int i = tid; i < SCAN_CHUNK; i += 256) {
        int idx = b * SCAN_CHUNK + i;
        if (idx < N_NODES) s += deg[idx];
    }
    red[tid] = s;
    __syncthreads();
    for (int st = 128; st > 0; st >>= 1) {
        if (tid < st) red[tid] += red[tid + st];
        __syncthreads();
    }
    if (tid == 0) bsum[b] = red[0];
}

__global__ __launch_bounds__(64) void k_scan_top(const int* __restrict__ bsum, int* __restrict__ boff) {
    int lane = threadIdx.x;
    int v = (lane < SCAN_NB) ? bsum[lane] : 0;
    int incl = v;
    for (int o = 1; o < 64; o <<= 1) {
        int t = __shfl_up(incl, o);
        if (lane >= o) incl += t;
    }
    boff[lane] = incl - v;
}

__global__ __launch_bounds__(256) void k_scan_chunk(const int* __restrict__ deg, const int* __restrict__ boff,
                                                   int* __restrict__ off) {
    __shared__ int wsum[4];
    int b = blockIdx.x, tid = threadIdx.x;
    int lane = tid & 63, wid = tid >> 6;
    int base = b * SCAN_CHUNK + tid * 4;
    int d[4];
#pragma unroll
    for (int j = 0; j < 4; ++j) d[j] = (base + j < N_NODES) ? deg[base + j] : 0;
    int tsum = d[0] + d[1] + d[2] + d[3];
    int incl = tsum;
    for (int o = 1; o < 64; o <<= 1) {
        int t = __shfl_up(incl, o);
        if (lane >= o) incl += t;
    }
    int wexcl = incl - tsum;
    if (lane == 63) wsum[wid] = incl;
    __syncthreads();
    int wbase = 0;
    for (int w = 0; w < wid; ++w) wbase += wsum[w];
    int run = boff[b] + wbase + wexcl;
#pragma unroll
    for (int j = 0; j < 4; ++j) {
        if (base + j < N_NODES) off[base + j] = run;
        run += d[j];
    }
    if (b == 0 && tid == 0) off[N_NODES] = ET;
}

__global__ __launch_bounds__(256) void k_scatter(const int* __restrict__ ei, const int* __restrict__ off,
                                                 int* __restrict__ cur, int* __restrict__ esrc) {
    int e = blockIdx.x * 256 + threadIdx.x;
    if (e >= ET) return;
    int u, v;
    if (e < N_EDGES) { u = ei[e]; v = ei[N_EDGES + e]; } else { u = e - N_EDGES; v = u; }
    if (v < 0 || v >= N_NODES) return;
    int p = off[v] + atomicAdd(&cur[v], 1);
    esrc[p] = u;
}

// ---------------- GEMM1: h1 = x @ W1  (50000x256 @ 256x256, fp32 in, bf16 out) ----------------

__global__ __launch_bounds__(256) void k_gemm1(const float* __restrict__ X, const float* __restrict__ W,
                                               unsigned short* __restrict__ H) {
    __shared__ float AsT[16][68];
    __shared__ float Bs[16][64];
    int tid = threadIdx.x;
    int row0 = blockIdx.x * 64;
    int col0 = blockIdx.y * 64;
    int tx = tid & 15, ty = tid >> 4;
    int ar = tid >> 2;
    int ak = (tid & 3) * 4;
    int bk = tid >> 4;
    int bc = (tid & 15) * 4;
    float acc[4][4] = {};
    for (int k0 = 0; k0 < 256; k0 += 16) {
        float4 av = make_float4(0.f, 0.f, 0.f, 0.f);
        if (row0 + ar < N_NODES) av = *(const float4*)(X + (size_t)(row0 + ar) * 256 + k0 + ak);
        AsT[ak + 0][ar] = av.x; AsT[ak + 1][ar] = av.y; AsT[ak + 2][ar] = av.z; AsT[ak + 3][ar] = av.w;
        *(float4*)&Bs[bk][bc] = *(const float4*)(W + (size_t)(k0 + bk) * 256 + col0 + bc);
        __syncthreads();
#pragma unroll
        for (int k = 0; k < 16; ++k) {
            float4 avv = *(const float4*)&AsT[k][ty * 4];
            float4 bvv = *(const float4*)&Bs[k][tx * 4];
            float aa[4] = {avv.x, avv.y, avv.z, avv.w};
            float bb[4] = {bvv.x, bvv.y, bvv.z, bvv.w};
#pragma unroll
            for (int j = 0; j < 4; ++j)
#pragma unroll
                for (int i = 0; i < 4; ++i) acc[j][i] = fmaf(aa[j], bb[i], acc[j][i]);
        }
        __syncthreads();
    }
#pragma unroll
    for (int j = 0; j < 4; ++j) {
        int row = row0 + ty * 4 + j;
        if (row < N_NODES) {
            ushort4 o;
            o.x = f2bf(acc[j][0]); o.y = f2bf(acc[j][1]);
            o.z = f2bf(acc[j][2]); o.w = f2bf(acc[j][3]);
            *(ushort4*)(H + (size_t)row * 256 + col0 + tx * 4) = o;
        }
    }
}

// ---------------- Layer-1 attention logits (reads bf16 h1) ----------------

__global__ __launch_bounds__(256) void k_logits1(const unsigned short* __restrict__ H,
                                                 const float* __restrict__ a_src,
                                                 const float* __restrict__ a_dst, float* __restrict__ als,
                                                 float* __restrict__ ald) {
    int wid = (blockIdx.x * 256 + threadIdx.x) >> 6;
    int lane = threadIdx.x & 63;
    if (wid >= N_NODES) return;
    ushort4 hv = *(const ushort4*)(H + (size_t)wid * 256 + lane * 4);
    float hx = bf2f(hv.x), hy = bf2f(hv.y), hz = bf2f(hv.z), hw = bf2f(hv.w);
    float4 as = *(const float4*)(a_src + lane * 4);
    float4 ad = *(const float4*)(a_dst + lane * 4);
    float ps = hx * as.x + hy * as.y + hz * as.z + hw * as.w;
    float pd = hx * ad.x + hy * ad.y + hz * ad.z + hw * ad.w;
#pragma unroll
    for (int m = 8; m >= 1; m >>= 1) { ps += __shfl_xor(ps, m); pd += __shfl_xor(pd, m); }
    if ((lane & 15) == 0) {
        als[wid * 4 + (lane >> 4)] = ps;
        ald[wid * 4 + (lane >> 4)] = pd;
    }
}

// ---------------- Fused: layer-1 aggregation + bias + ELU + GEMM2 + layer-2 logits ----------------
// 4 waves/block, one node per wave. No segment-max: softmax is shift-invariant and
// logits are bounded (|e| <~ 6), so exp(e) is fp32-safe -> accumulator chain is pure FMA,
// exp is independent per-edge work. W2 in LDS as bf16: 20.5KB LDS -> 8 blocks/CU (100% occ).

__global__ __launch_bounds__(256) void k_agg1g2(const unsigned short* __restrict__ H1,
                                                const float* __restrict__ als, const float* __restrict__ ald_,
                                                const int* __restrict__ off, const int* __restrict__ esrc,
                                                const float* __restrict__ b1, const float* __restrict__ W2,
                                                const float* __restrict__ as2, const float* __restrict__ ad2,
                                                float* __restrict__ G, float* __restrict__ als2,
                                                float* __restrict__ ald2) {
    __shared__ unsigned short Ws[256 * 32];   // bf16 W2
    __shared__ float h2buf[4][256];
    int tid = threadIdx.x;
    for (int i = tid; i < 2048; i += 256) {   // 8192 floats / 4
        float4 w = ((const float4*)W2)[i];
        ushort4 o; o.x = f2bf(w.x); o.y = f2bf(w.y); o.z = f2bf(w.z); o.w = f2bf(w.w);
        ((ushort4*)Ws)[i] = o;
    }
    int wv = tid >> 6, lane = tid & 63;
    int node = blockIdx.x * 4 + wv;   // always < N_NODES (12500*4 == 50000)
    int head = lane >> 4;
    float ald = ald_[node * 4 + head];
    int pstart = off[node], pend = off[node + 1];
    float l = 0.f, ax = 0.f, ay = 0.f, az = 0.f, aw = 0.f;
    const ushort4* H4 = (const ushort4*)H1;
    int p = pstart;
    for (; p + 1 < pend; p += 2) {
        int u0 = esrc[p], u1 = esrc[p + 1];
        ushort4 h0 = H4[(size_t)u0 * 64 + lane];
        ushort4 h1v = H4[(size_t)u1 * 64 + lane];
        float e0 = als[u0 * 4 + head] + ald;
        float e1 = als[u1 * 4 + head] + ald;
        e0 = e0 > 0.f ? e0 : NEG_SLOPE * e0;
        e1 = e1 > 0.f ? e1 : NEG_SLOPE * e1;
        float pw0 = __expf(e0), pw1 = __expf(e1);
        l += pw0 + pw1;
        ax = fmaf(pw1, bf2f(h1v.x), fmaf(pw0, bf2f(h0.x), ax));
        ay = fmaf(pw1, bf2f(h1v.y), fmaf(pw0, bf2f(h0.y), ay));
        az = fmaf(pw1, bf2f(h1v.z), fmaf(pw0, bf2f(h0.z), az));
        aw = fmaf(pw1, bf2f(h1v.w), fmaf(pw0, bf2f(h0.w), aw));
    }
    if (p < pend) {
        int u0 = esrc[p];
        ushort4 h0 = H4[(size_t)u0 * 64 + lane];
        float e0 = als[u0 * 4 + head] + ald;
        e0 = e0 > 0.f ? e0 : NEG_SLOPE * e0;
        float pw0 = __expf(e0);
        l += pw0;
        ax = fmaf(pw0, bf2f(h0.x), ax);
        ay = fmaf(pw0, bf2f(h0.y), ay);
        az = fmaf(pw0, bf2f(h0.z), az);
        aw = fmaf(pw0, bf2f(h0.w), aw);
    }
    float inv = 1.f / l;
    int c = lane * 4;
    float4 bb = *(const float4*)(b1 + c);
    float o0 = ax * inv + bb.x, o1 = ay * inv + bb.y, o2 = az * inv + bb.z, o3 = aw * inv + bb.w;
    o0 = o0 > 0.f ? o0 : expm1f(o0);
    o1 = o1 > 0.f ? o1 : expm1f(o1);
    o2 = o2 > 0.f ? o2 : expm1f(o2);
    o3 = o3 > 0.f ? o3 : expm1f(o3);
    *(float4*)&h2buf[wv][c] = make_float4(o0, o1, o2, o3);
    __syncthreads();   // covers W2 staging + h2buf cross-lane reads
    int col = lane & 31, half = lane >> 5;
    const float* hrow = h2buf[wv];
    float sum = 0.f;
    int j0 = half * 128;
#pragma unroll 8
    for (int j = j0; j < j0 + 128; ++j) sum = fmaf(hrow[j], bf2f(Ws[j * 32 + col]), sum);
    float g = sum + __shfl_xor(sum, 32);
    if (half == 0) G[(size_t)node * 32 + col] = g;
    float ps = g * as2[col];
    float pd = g * ad2[col];
#pragma unroll
    for (int msk = 16; msk >= 1; msk >>= 1) { ps += __shfl_xor(ps, msk); pd += __shfl_xor(pd, msk); }
    if (lane == 0) { als2[node] = ps; ald2[node] = pd; }
}

// ---------------- Layer-2 aggregation + bias + log_softmax (no segment-max) ----------------

__global__ __launch_bounds__(256) void k_agg2(const float* __restrict__ G, const float* __restrict__ als2,
                                              const float* __restrict__ ald2_, const int* __restrict__ off,
                                              const int* __restrict__ esrc, const float* __restrict__ b2,
                                              float* __restrict__ out) {
    int gid = blockIdx.x * 256 + threadIdx.x;
    int node = gid >> 5;
    int col = gid & 31;
    if (node >= N_NODES) return;
    float ald = ald2_[node];
    int pstart = off[node], pend = off[node + 1];
    float l = 0.f, acc = 0.f;
    int p = pstart;
    for (; p + 1 < pend; p += 2) {
        int u0 = esrc[p], u1 = esrc[p + 1];
        float g0 = G[(size_t)u0 * 32 + col];
        float g1 = G[(size_t)u1 * 32 + col];
        float e0 = als2[u0] + ald;
        float e1 = als2[u1] + ald;
        e0 = e0 > 0.f ? e0 : NEG_SLOPE * e0;
        e1 = e1 > 0.f ? e1 : NEG_SLOPE * e1;
        float pw0 = __expf(e0), pw1 = __expf(e1);
        l += pw0 + pw1;
        acc = fmaf(pw1, g1, fmaf(pw0, g0, acc));
    }
    if (p < pend) {
        int u0 = esrc[p];
        float g0 = G[(size_t)u0 * 32 + col];
        float e0 = als2[u0] + ald;
        e0 = e0 > 0.f ? e0 : NEG_SLOPE * e0;
        float pw0 = __expf(e0);
        l += pw0;
        acc = fmaf(pw0, g0, acc);
    }
    float o = acc / l + b2[col];
    float mm = o;
#pragma unroll
    for (int msk = 16; msk >= 1; msk >>= 1) mm = fmaxf(mm, __shfl_xor(mm, msk));
    float ex = __expf(o - mm);
    float s = ex;
#pragma unroll
    for (int msk = 16; msk >= 1; msk >>= 1) s += __shfl_xor(s, msk);
    out[(size_t)node * 32 + col] = o - mm - logf(s);
}

// ---------------- launch ----------------

extern "C" void kernel_launch(void* const* d_in, const int* in_sizes, int n_in,
                              void* d_out, int out_size, void* d_ws, size_t ws_size,
                              hipStream_t stream) {
    const float* x   = (const float*)d_in[0];
    const int*   ei  = (const int*)d_in[1];
    const float* W1  = (const float*)d_in[2];
    const float* as1 = (const float*)d_in[3];
    const float* ad1 = (const float*)d_in[4];
    const float* b1  = (const float*)d_in[5];
    const float* W2  = (const float*)d_in[6];
    const float* as2 = (const float*)d_in[7];
    const float* ad2 = (const float*)d_in[8];
    const float* b2  = (const float*)d_in[9];
    float* out = (float*)d_out;

    char* p = (char*)d_ws;
    auto alloc = [&](size_t bytes) {
        char* r = p;
        p += (bytes + 255) & ~(size_t)255;
        return r;
    };
    // total workspace ~38 MB (keep small: larger footprints overflowed d_ws in round 1)
    unsigned short* h1 = (unsigned short*)alloc((size_t)N_NODES * 256 * 2);  // 25.6 MB bf16
    float* g    = (float*)alloc((size_t)N_NODES * 32 * 4);                   // 6.4 MB
    float* als1 = (float*)alloc((size_t)N_NODES * 4 * 4);
    float* ald1 = (float*)alloc((size_t)N_NODES * 4 * 4);
    float* als2 = (float*)alloc((size_t)N_NODES * 4);
    float* ald2 = (float*)alloc((size_t)N_NODES * 4);
    int* deg  = (int*)alloc((size_t)N_NODES * 4);
    int* cur  = (int*)alloc((size_t)N_NODES * 4);
    int* off  = (int*)alloc((size_t)(N_NODES + 1) * 4);
    int* bsum = (int*)alloc(64 * 4);
    int* boff = (int*)alloc(64 * 4);
    int* esrc = (int*)alloc((size_t)ET * 4);                                 // 3.4 MB

    hipMemsetAsync(deg, 0, (size_t)N_NODES * 4, stream);
    hipMemsetAsync(cur, 0, (size_t)N_NODES * 4, stream);

    k_hist<<<(ET + 255) / 256, 256, 0, stream>>>(ei, deg);
    k_scan_reduce<<<SCAN_NB, 256, 0, stream>>>(deg, bsum);
    k_scan_top<<<1, 64, 0, stream>>>(bsum, boff);
    k_scan_chunk<<<SCAN_NB, 256, 0, stream>>>(deg, boff, off);
    k_scatter<<<(ET + 255) / 256, 256, 0, stream>>>(ei, off, cur, esrc);

    k_gemm1<<<dim3((N_NODES + 63) / 64, 4), 256, 0, stream>>>(x, W1, h1);
    k_logits1<<<(N_NODES + 3) / 4, 256, 0, stream>>>(h1, as1, ad1, als1, ald1);
    k_agg1g2<<<N_NODES / 4, 256, 0, stream>>>(h1, als1, ald1, off, esrc, b1, W2, as2, ad2,
                                              g, als2, ald2);
    k_agg2<<<(N_NODES + 7) / 8, 256, 0, stream>>>(g, als2, ald2, off, esrc, b2, out);
}

// Round 4
// 350.444 us; speedup vs baseline: 1.6111x; 1.2008x over previous
//
#include <hip/hip_runtime.h>
#include <math.h>

#define N_NODES 50000
#define N_EDGES 800000
#define ET (N_EDGES + N_NODES)   // edges + self loops
#define NEG_SLOPE 0.2f

#define SCAN_CHUNK 1024
#define SCAN_NB ((N_NODES + SCAN_CHUNK - 1) / SCAN_CHUNK)  // 49

typedef __attribute__((ext_vector_type(8))) short s16x8;
typedef __attribute__((ext_vector_type(4))) float f32x4;

__device__ __forceinline__ unsigned short f2bf(float f) {
    union { float f; unsigned u; } v; v.f = f;
    unsigned r = v.u + 0x7FFF + ((v.u >> 16) & 1);  // RNE
    return (unsigned short)(r >> 16);
}
__device__ __forceinline__ float bf2f(unsigned short s) {
    union { unsigned u; float f; } v; v.u = ((unsigned)s) << 16;
    return v.f;
}
// truncation-pack 8 fp32 -> 8 bf16 (cheap: 2 VALU per 2 elems; error ~2^-9 rel, fine vs 0.079 budget)
__device__ __forceinline__ uint4 pack_bf16_trunc(float4 f0, float4 f1) {
    const unsigned* a = (const unsigned*)&f0;
    const unsigned* b = (const unsigned*)&f1;
    uint4 r;
    r.x = (a[0] >> 16) | (a[1] & 0xffff0000u);
    r.y = (a[2] >> 16) | (a[3] & 0xffff0000u);
    r.z = (b[0] >> 16) | (b[1] & 0xffff0000u);
    r.w = (b[2] >> 16) | (b[3] & 0xffff0000u);
    return r;
}

// ---------------- CSR build ----------------

__global__ __launch_bounds__(256) void k_hist(const int* __restrict__ ei, int* __restrict__ deg) {
    int e = blockIdx.x * 256 + threadIdx.x;
    if (e >= ET) return;
    int v = (e < N_EDGES) ? ei[N_EDGES + e] : (e - N_EDGES);
    if (v >= 0 && v < N_NODES) atomicAdd(&deg[v], 1);
}

__global__ __launch_bounds__(256) void k_scan_reduce(const int* __restrict__ deg, int* __restrict__ bsum) {
    __shared__ int red[256];
    int b = blockIdx.x, tid = threadIdx.x;
    int s = 0;
    for (int i = tid; i < SCAN_CHUNK; i += 256) {
        int idx = b * SCAN_CHUNK + i;
        if (idx < N_NODES) s += deg[idx];
    }
    red[tid] = s;
    __syncthreads();
    for (int st = 128; st > 0; st >>= 1) {
        if (tid < st) red[tid] += red[tid + st];
        __syncthreads();
    }
    if (tid == 0) bsum[b] = red[0];
}

__global__ __launch_bounds__(64) void k_scan_top(const int* __restrict__ bsum, int* __restrict__ boff) {
    int lane = threadIdx.x;
    int v = (lane < SCAN_NB) ? bsum[lane] : 0;
    int incl = v;
    for (int o = 1; o < 64; o <<= 1) {
        int t = __shfl_up(incl, o);
        if (lane >= o) incl += t;
    }
    boff[lane] = incl - v;
}

__global__ __launch_bounds__(256) void k_scan_chunk(const int* __restrict__ deg, const int* __restrict__ boff,
                                                   int* __restrict__ off) {
    __shared__ int wsum[4];
    int b = blockIdx.x, tid = threadIdx.x;
    int lane = tid & 63, wid = tid >> 6;
    int base = b * SCAN_CHUNK + tid * 4;
    int d[4];
#pragma unroll
    for (int j = 0; j < 4; ++j) d[j] = (base + j < N_NODES) ? deg[base + j] : 0;
    int tsum = d[0] + d[1] + d[2] + d[3];
    int incl = tsum;
    for (int o = 1; o < 64; o <<= 1) {
        int t = __shfl_up(incl, o);
        if (lane >= o) incl += t;
    }
    int wexcl = incl - tsum;
    if (lane == 63) wsum[wid] = incl;
    __syncthreads();
    int wbase = 0;
    for (int w = 0; w < wid; ++w) wbase += wsum[w];
    int run = boff[b] + wbase + wexcl;
#pragma unroll
    for (int j = 0; j < 4; ++j) {
        if (base + j < N_NODES) off[base + j] = run;
        run += d[j];
    }
    if (b == 0 && tid == 0) off[N_NODES] = ET;
}

__global__ __launch_bounds__(256) void k_scatter(const int* __restrict__ ei, const int* __restrict__ off,
                                                 int* __restrict__ cur, int* __restrict__ esrc) {
    int e = blockIdx.x * 256 + threadIdx.x;
    if (e >= ET) return;
    int u, v;
    if (e < N_EDGES) { u = ei[e]; v = ei[N_EDGES + e]; } else { u = e - N_EDGES; v = u; }
    if (v < 0 || v >= N_NODES) return;
    int p = off[v] + atomicAdd(&cur[v], 1);
    esrc[p] = u;
}

// ---------------- W1 -> bf16 transposed [n][k] (tiny, off hot path, RNE) ----------------

__global__ __launch_bounds__(256) void k_cvtw(const float* __restrict__ W1, unsigned short* __restrict__ WT) {
    int n = blockIdx.x, k = threadIdx.x;
    WT[n * 256 + k] = f2bf(W1[k * 256 + n]);
}

// ---------------- GEMM1 via MFMA: h1 = bf16(x) @ bf16(W1), out bf16 ----------------
// BM=128 BN=64 BK=32, 256 thr (4 waves), each wave -> 64x32 via 4x2 of 16x16x32 MFMAs.
// x converted fp32->bf16 (trunc) during LDS staging (avoids an xb workspace buffer).
// LDS rows padded to 40 bf16 (80B, 16B-aligned): fragment ds_read_b128 -> 2-way banks (free).

__global__ __launch_bounds__(256) void k_gemm1m(const float* __restrict__ X, const unsigned short* __restrict__ WT,
                                                unsigned short* __restrict__ H) {
    __shared__ unsigned short As[128][40];
    __shared__ unsigned short Bs[64][40];
    int tid = threadIdx.x;
    int row0 = blockIdx.x * 128;
    int col0 = blockIdx.y * 64;
    int wv = tid >> 6, lane = tid & 63;
    int wm = wv & 1, wn = wv >> 1;
    int lr = lane & 15, quad = lane >> 4;
    f32x4 acc[4][2];
#pragma unroll
    for (int mt = 0; mt < 4; ++mt)
#pragma unroll
        for (int nt = 0; nt < 2; ++nt) acc[mt][nt] = (f32x4){0.f, 0.f, 0.f, 0.f};

    for (int k0 = 0; k0 < 256; k0 += 32) {
#pragma unroll
        for (int pass = 0; pass < 2; ++pass) {
            int u = tid + pass * 256;
            int r = u >> 2, seg = u & 3;
            int grow = row0 + r;
            float4 f0 = make_float4(0.f, 0.f, 0.f, 0.f), f1 = f0;
            if (grow < N_NODES) {
                const float* src = X + (size_t)grow * 256 + k0 + seg * 8;
                f0 = *(const float4*)src;
                f1 = *(const float4*)(src + 4);
            }
            *(uint4*)&As[r][seg * 8] = pack_bf16_trunc(f0, f1);
        }
        {
            int n = tid >> 2, seg = tid & 3;
            uint4 v = *(const uint4*)(WT + ((col0 + n) << 8) + k0 + seg * 8);
            *(uint4*)&Bs[n][seg * 8] = v;
        }
        __syncthreads();
        s16x8 a[4], b[2];
#pragma unroll
        for (int mt = 0; mt < 4; ++mt) a[mt] = *(const s16x8*)&As[wm * 64 + mt * 16 + lr][quad * 8];
#pragma unroll
        for (int nt = 0; nt < 2; ++nt) b[nt] = *(const s16x8*)&Bs[wn * 32 + nt * 16 + lr][quad * 8];
#pragma unroll
        for (int mt = 0; mt < 4; ++mt)
#pragma unroll
            for (int nt = 0; nt < 2; ++nt)
                acc[mt][nt] = __builtin_amdgcn_mfma_f32_16x16x32_bf16(a[mt], b[nt], acc[mt][nt], 0, 0, 0);
        __syncthreads();
    }
    // C/D layout: col = lane&15, row = quad*4 + reg  [verified m89/m91]
#pragma unroll
    for (int mt = 0; mt < 4; ++mt) {
#pragma unroll
        for (int r = 0; r < 4; ++r) {
            int row = row0 + wm * 64 + mt * 16 + quad * 4 + r;
            if (row < N_NODES) {
#pragma unroll
                for (int nt = 0; nt < 2; ++nt)
                    H[(size_t)row * 256 + col0 + wn * 32 + nt * 16 + lr] = f2bf(acc[mt][nt][r]);
            }
        }
    }
}

// ---------------- Layer-1 attention logits (reads bf16 h1) ----------------

__global__ __launch_bounds__(256) void k_logits1(const unsigned short* __restrict__ H,
                                                 const float* __restrict__ a_src,
                                                 const float* __restrict__ a_dst, float* __restrict__ als,
                                                 float* __restrict__ ald) {
    int wid = (blockIdx.x * 256 + threadIdx.x) >> 6;
    int lane = threadIdx.x & 63;
    if (wid >= N_NODES) return;
    ushort4 hv = *(const ushort4*)(H + (size_t)wid * 256 + lane * 4);
    float hx = bf2f(hv.x), hy = bf2f(hv.y), hz = bf2f(hv.z), hw = bf2f(hv.w);
    float4 as = *(const float4*)(a_src + lane * 4);
    float4 ad = *(const float4*)(a_dst + lane * 4);
    float ps = hx * as.x + hy * as.y + hz * as.z + hw * as.w;
    float pd = hx * ad.x + hy * ad.y + hz * ad.z + hw * ad.w;
#pragma unroll
    for (int m = 8; m >= 1; m >>= 1) { ps += __shfl_xor(ps, m); pd += __shfl_xor(pd, m); }
    if ((lane & 15) == 0) {
        als[wid * 4 + (lane >> 4)] = ps;
        ald[wid * 4 + (lane >> 4)] = pd;
    }
}

// ---------------- Fused: layer-1 aggregation + bias + ELU + GEMM2 + layer-2 logits ----------------
// 4 waves/block, one node per wave, unroll-4 gather loop (4 outstanding row-gathers).
// No segment-max (logits bounded, exp fp32-safe). W2 bf16 in LDS -> 20.5KB, 8 blocks/CU.

__global__ __launch_bounds__(256) void k_agg1g2(const unsigned short* __restrict__ H1,
                                                const float* __restrict__ als, const float* __restrict__ ald_,
                                                const int* __restrict__ off, const int* __restrict__ esrc,
                                                const float* __restrict__ b1, const float* __restrict__ W2,
                                                const float* __restrict__ as2, const float* __restrict__ ad2,
                                                unsigned short* __restrict__ Gb, float* __restrict__ als2,
                                                float* __restrict__ ald2) {
    __shared__ unsigned short Ws[256 * 32];   // bf16 W2
    __shared__ float h2buf[4][256];
    int tid = threadIdx.x;
    for (int i = tid; i < 2048; i += 256) {
        float4 w = ((const float4*)W2)[i];
        ushort4 o; o.x = f2bf(w.x); o.y = f2bf(w.y); o.z = f2bf(w.z); o.w = f2bf(w.w);
        ((ushort4*)Ws)[i] = o;
    }
    int wv = tid >> 6, lane = tid & 63;
    int node = blockIdx.x * 4 + wv;   // 12500*4 == 50000, no bounds check
    int head = lane >> 4;
    float ald = ald_[node * 4 + head];
    int pstart = off[node], pend = off[node + 1];
    float l = 0.f, ax = 0.f, ay = 0.f, az = 0.f, aw = 0.f;
    const ushort4* H4 = (const ushort4*)H1;
    int p = pstart;
    for (; p + 3 < pend; p += 4) {
        int u0 = esrc[p], u1 = esrc[p + 1], u2 = esrc[p + 2], u3 = esrc[p + 3];
        ushort4 h0 = H4[(size_t)u0 * 64 + lane];
        ushort4 h1v = H4[(size_t)u1 * 64 + lane];
        ushort4 h2v = H4[(size_t)u2 * 64 + lane];
        ushort4 h3v = H4[(size_t)u3 * 64 + lane];
        float e0 = als[u0 * 4 + head] + ald;
        float e1 = als[u1 * 4 + head] + ald;
        float e2 = als[u2 * 4 + head] + ald;
        float e3 = als[u3 * 4 + head] + ald;
        e0 = e0 > 0.f ? e0 : NEG_SLOPE * e0;
        e1 = e1 > 0.f ? e1 : NEG_SLOPE * e1;
        e2 = e2 > 0.f ? e2 : NEG_SLOPE * e2;
        e3 = e3 > 0.f ? e3 : NEG_SLOPE * e3;
        float pw0 = __expf(e0), pw1 = __expf(e1), pw2 = __expf(e2), pw3 = __expf(e3);
        l += (pw0 + pw1) + (pw2 + pw3);
        ax = fmaf(pw3, bf2f(h3v.x), fmaf(pw2, bf2f(h2v.x), fmaf(pw1, bf2f(h1v.x), fmaf(pw0, bf2f(h0.x), ax))));
        ay = fmaf(pw3, bf2f(h3v.y), fmaf(pw2, bf2f(h2v.y), fmaf(pw1, bf2f(h1v.y), fmaf(pw0, bf2f(h0.y), ay))));
        az = fmaf(pw3, bf2f(h3v.z), fmaf(pw2, bf2f(h2v.z), fmaf(pw1, bf2f(h1v.z), fmaf(pw0, bf2f(h0.z), az))));
        aw = fmaf(pw3, bf2f(h3v.w), fmaf(pw2, bf2f(h2v.w), fmaf(pw1, bf2f(h1v.w), fmaf(pw0, bf2f(h0.w), aw))));
    }
    for (; p < pend; ++p) {
        int u0 = esrc[p];
        ushort4 h0 = H4[(size_t)u0 * 64 + lane];
        float e0 = als[u0 * 4 + head] + ald;
        e0 = e0 > 0.f ? e0 : NEG_SLOPE * e0;
        float pw0 = __expf(e0);
        l += pw0;
        ax = fmaf(pw0, bf2f(h0.x), ax);
        ay = fmaf(pw0, bf2f(h0.y), ay);
        az = fmaf(pw0, bf2f(h0.z), az);
        aw = fmaf(pw0, bf2f(h0.w), aw);
    }
    float inv = 1.f / l;
    int c = lane * 4;
    float4 bb = *(const float4*)(b1 + c);
    float o0 = ax * inv + bb.x, o1 = ay * inv + bb.y, o2 = az * inv + bb.z, o3 = aw * inv + bb.w;
    o0 = o0 > 0.f ? o0 : expm1f(o0);
    o1 = o1 > 0.f ? o1 : expm1f(o1);
    o2 = o2 > 0.f ? o2 : expm1f(o2);
    o3 = o3 > 0.f ? o3 : expm1f(o3);
    *(float4*)&h2buf[wv][c] = make_float4(o0, o1, o2, o3);
    __syncthreads();
    int col = lane & 31, half = lane >> 5;
    const float* hrow = h2buf[wv];
    float sum = 0.f;
    int j0 = half * 128;
#pragma unroll 8
    for (int j = j0; j < j0 + 128; ++j) sum = fmaf(hrow[j], bf2f(Ws[j * 32 + col]), sum);
    float g = sum + __shfl_xor(sum, 32);
    if (half == 0) Gb[(size_t)node * 32 + col] = f2bf(g);
    float ps = g * as2[col];
    float pd = g * ad2[col];
#pragma unroll
    for (int msk = 16; msk >= 1; msk >>= 1) { ps += __shfl_xor(ps, msk); pd += __shfl_xor(pd, msk); }
    if (lane == 0) { als2[node] = ps; ald2[node] = pd; }
}

// ---------------- Layer-2 aggregation + bias + log_softmax (bf16 G, unroll-4) ----------------

__global__ __launch_bounds__(256) void k_agg2(const unsigned short* __restrict__ Gb,
                                              const float* __restrict__ als2,
                                              const float* __restrict__ ald2_, const int* __restrict__ off,
                                              const int* __restrict__ esrc, const float* __restrict__ b2,
                                              float* __restrict__ out) {
    int gid = blockIdx.x * 256 + threadIdx.x;
    int node = gid >> 5;
    int col = gid & 31;
    if (node >= N_NODES) return;
    float ald = ald2_[node];
    int pstart = off[node], pend = off[node + 1];
    float l = 0.f, acc = 0.f;
    int p = pstart;
    for (; p + 3 < pend; p += 4) {
        int u0 = esrc[p], u1 = esrc[p + 1], u2 = esrc[p + 2], u3 = esrc[p + 3];
        float g0 = bf2f(Gb[(size_t)u0 * 32 + col]);
        float g1 = bf2f(Gb[(size_t)u1 * 32 + col]);
        float g2 = bf2f(Gb[(size_t)u2 * 32 + col]);
        float g3 = bf2f(Gb[(size_t)u3 * 32 + col]);
        float e0 = als2[u0] + ald;
        float e1 = als2[u1] + ald;
        float e2 = als2[u2] + ald;
        float e3 = als2[u3] + ald;
        e0 = e0 > 0.f ? e0 : NEG_SLOPE * e0;
        e1 = e1 > 0.f ? e1 : NEG_SLOPE * e1;
        e2 = e2 > 0.f ? e2 : NEG_SLOPE * e2;
        e3 = e3 > 0.f ? e3 : NEG_SLOPE * e3;
        float pw0 = __expf(e0), pw1 = __expf(e1), pw2 = __expf(e2), pw3 = __expf(e3);
        l += (pw0 + pw1) + (pw2 + pw3);
        acc = fmaf(pw3, g3, fmaf(pw2, g2, fmaf(pw1, g1, fmaf(pw0, g0, acc))));
    }
    for (; p < pend; ++p) {
        int u0 = esrc[p];
        float g0 = bf2f(Gb[(size_t)u0 * 32 + col]);
        float e0 = als2[u0] + ald;
        e0 = e0 > 0.f ? e0 : NEG_SLOPE * e0;
        float pw0 = __expf(e0);
        l += pw0;
        acc = fmaf(pw0, g0, acc);
    }
    float o = acc / l + b2[col];
    float mm = o;
#pragma unroll
    for (int msk = 16; msk >= 1; msk >>= 1) mm = fmaxf(mm, __shfl_xor(mm, msk));
    float ex = __expf(o - mm);
    float s = ex;
#pragma unroll
    for (int msk = 16; msk >= 1; msk >>= 1) s += __shfl_xor(s, msk);
    out[(size_t)node * 32 + col] = o - mm - logf(s);
}

// ---------------- launch ----------------

extern "C" void kernel_launch(void* const* d_in, const int* in_sizes, int n_in,
                              void* d_out, int out_size, void* d_ws, size_t ws_size,
                              hipStream_t stream) {
    const float* x   = (const float*)d_in[0];
    const int*   ei  = (const int*)d_in[1];
    const float* W1  = (const float*)d_in[2];
    const float* as1 = (const float*)d_in[3];
    const float* ad1 = (const float*)d_in[4];
    const float* b1  = (const float*)d_in[5];
    const float* W2  = (const float*)d_in[6];
    const float* as2 = (const float*)d_in[7];
    const float* ad2 = (const float*)d_in[8];
    const float* b2  = (const float*)d_in[9];
    float* out = (float*)d_out;

    char* p = (char*)d_ws;
    auto alloc = [&](size_t bytes) {
        char* r = p;
        p += (bytes + 255) & ~(size_t)255;
        return r;
    };
    // workspace ~35 MB total (ws overflow above ~38-115 MB corrupts harness state — keep small)
    unsigned short* h1 = (unsigned short*)alloc((size_t)N_NODES * 256 * 2);  // 25.6 MB bf16
    unsigned short* wt = (unsigned short*)alloc((size_t)256 * 256 * 2);      // 128 KB bf16 W1^T
    unsigned short* g  = (unsigned short*)alloc((size_t)N_NODES * 32 * 2);   // 3.2 MB bf16
    float* als1 = (float*)alloc((size_t)N_NODES * 4 * 4);
    float* ald1 = (float*)alloc((size_t)N_NODES * 4 * 4);
    float* als2 = (float*)alloc((size_t)N_NODES * 4);
    float* ald2 = (float*)alloc((size_t)N_NODES * 4);
    int* deg  = (int*)alloc((size_t)N_NODES * 4);
    int* cur  = (int*)alloc((size_t)N_NODES * 4);
    int* off  = (int*)alloc((size_t)(N_NODES + 1) * 4);
    int* bsum = (int*)alloc(64 * 4);
    int* boff = (int*)alloc(64 * 4);
    int* esrc = (int*)alloc((size_t)ET * 4);                                 // 3.4 MB

    hipMemsetAsync(deg, 0, (size_t)N_NODES * 4, stream);
    hipMemsetAsync(cur, 0, (size_t)N_NODES * 4, stream);

    k_hist<<<(ET + 255) / 256, 256, 0, stream>>>(ei, deg);
    k_scan_reduce<<<SCAN_NB, 256, 0, stream>>>(deg, bsum);
    k_scan_top<<<1, 64, 0, stream>>>(bsum, boff);
    k_scan_chunk<<<SCAN_NB, 256, 0, stream>>>(deg, boff, off);
    k_scatter<<<(ET + 255) / 256, 256, 0, stream>>>(ei, off, cur, esrc);

    k_cvtw<<<256, 256, 0, stream>>>(W1, wt);
    k_gemm1m<<<dim3((N_NODES + 127) / 128, 4), 256, 0, stream>>>(x, wt, h1);
    k_logits1<<<(N_NODES + 3) / 4, 256, 0, stream>>>(h1, as1, ad1, als1, ald1);
    k_agg1g2<<<N_NODES / 4, 256, 0, stream>>>(h1, als1, ald1, off, esrc, b1, W2, as2, ad2,
                                              g, als2, ald2);
    k_agg2<<<(N_NODES + 7) / 8, 256, 0, stream>>>(g, als2, ald2, off, esrc, b2, out);
}

// Round 5
// 333.583 us; speedup vs baseline: 1.6926x; 1.0505x over previous
//
#include <hip/hip_runtime.h>
#include <math.h>

#define N_NODES 50000
#define N_EDGES 800000
#define ET (N_EDGES + N_NODES)   // edges + self loops
#define NEG_SLOPE 0.2f

#define SCAN_CHUNK 1024
#define SCAN_NB ((N_NODES + SCAN_CHUNK - 1) / SCAN_CHUNK)  // 49

typedef __attribute__((ext_vector_type(8))) short s16x8;
typedef __attribute__((ext_vector_type(4))) float f32x4;

__device__ __forceinline__ unsigned short f2bf(float f) {
    union { float f; unsigned u; } v; v.f = f;
    unsigned r = v.u + 0x7FFF + ((v.u >> 16) & 1);  // RNE
    return (unsigned short)(r >> 16);
}
__device__ __forceinline__ float bf2f(unsigned short s) {
    union { unsigned u; float f; } v; v.u = ((unsigned)s) << 16;
    return v.f;
}
__device__ __forceinline__ float asf(unsigned u) {
    union { unsigned u; float f; } v; v.u = u;
    return v.f;
}
// truncation-pack 8 fp32 -> 8 bf16 (cheap; error ~2^-9 rel, fine vs 0.079 budget)
__device__ __forceinline__ uint4 pack_bf16_trunc(float4 f0, float4 f1) {
    const unsigned* a = (const unsigned*)&f0;
    const unsigned* b = (const unsigned*)&f1;
    uint4 r;
    r.x = (a[0] >> 16) | (a[1] & 0xffff0000u);
    r.y = (a[2] >> 16) | (a[3] & 0xffff0000u);
    r.z = (b[0] >> 16) | (b[1] & 0xffff0000u);
    r.w = (b[2] >> 16) | (b[3] & 0xffff0000u);
    return r;
}

// ---------------- CSR build ----------------

__global__ __launch_bounds__(256) void k_hist(const int* __restrict__ ei, int* __restrict__ deg) {
    int e = blockIdx.x * 256 + threadIdx.x;
    if (e >= ET) return;
    int v = (e < N_EDGES) ? ei[N_EDGES + e] : (e - N_EDGES);
    if (v >= 0 && v < N_NODES) atomicAdd(&deg[v], 1);
}

__global__ __launch_bounds__(256) void k_scan_reduce(const int* __restrict__ deg, int* __restrict__ bsum) {
    __shared__ int red[256];
    int b = blockIdx.x, tid = threadIdx.x;
    int s = 0;
    for (int i = tid; i < SCAN_CHUNK; i += 256) {
        int idx = b * SCAN_CHUNK + i;
        if (idx < N_NODES) s += deg[idx];
    }
    red[tid] = s;
    __syncthreads();
    for (int st = 128; st > 0; st >>= 1) {
        if (tid < st) red[tid] += red[tid + st];
        __syncthreads();
    }
    if (tid == 0) bsum[b] = red[0];
}

__global__ __launch_bounds__(64) void k_scan_top(const int* __restrict__ bsum, int* __restrict__ boff) {
    int lane = threadIdx.x;
    int v = (lane < SCAN_NB) ? bsum[lane] : 0;
    int incl = v;
    for (int o = 1; o < 64; o <<= 1) {
        int t = __shfl_up(incl, o);
        if (lane >= o) incl += t;
    }
    boff[lane] = incl - v;
}

__global__ __launch_bounds__(256) void k_scan_chunk(const int* __restrict__ deg, const int* __restrict__ boff,
                                                   int* __restrict__ off) {
    __shared__ int wsum[4];
    int b = blockIdx.x, tid = threadIdx.x;
    int lane = tid & 63, wid = tid >> 6;
    int base = b * SCAN_CHUNK + tid * 4;
    int d[4];
#pragma unroll
    for (int j = 0; j < 4; ++j) d[j] = (base + j < N_NODES) ? deg[base + j] : 0;
    int tsum = d[0] + d[1] + d[2] + d[3];
    int incl = tsum;
    for (int o = 1; o < 64; o <<= 1) {
        int t = __shfl_up(incl, o);
        if (lane >= o) incl += t;
    }
    int wexcl = incl - tsum;
    if (lane == 63) wsum[wid] = incl;
    __syncthreads();
    int wbase = 0;
    for (int w = 0; w < wid; ++w) wbase += wsum[w];
    int run = boff[b] + wbase + wexcl;
#pragma unroll
    for (int j = 0; j < 4; ++j) {
        if (base + j < N_NODES) off[base + j] = run;
        run += d[j];
    }
    if (b == 0 && tid == 0) off[N_NODES] = ET;
}

__global__ __launch_bounds__(256) void k_scatter(const int* __restrict__ ei, const int* __restrict__ off,
                                                 int* __restrict__ cur, int* __restrict__ esrc) {
    int e = blockIdx.x * 256 + threadIdx.x;
    if (e >= ET) return;
    int u, v;
    if (e < N_EDGES) { u = ei[e]; v = ei[N_EDGES + e]; } else { u = e - N_EDGES; v = u; }
    if (v < 0 || v >= N_NODES) return;
    int p = off[v] + atomicAdd(&cur[v], 1);
    esrc[p] = u;
}

// ---------------- weight converts: W1 -> bf16 W1^T [256][256]; W2 -> bf16 W2^T [32][256] ----------------

__global__ __launch_bounds__(256) void k_cvtw(const float* __restrict__ W1, const float* __restrict__ W2,
                                              unsigned short* __restrict__ WT, unsigned short* __restrict__ W2T) {
    int b = blockIdx.x, k = threadIdx.x;
    if (b < 256) {
        WT[b * 256 + k] = f2bf(W1[k * 256 + b]);
    } else {
        int c = b - 256;
        W2T[c * 256 + k] = f2bf(W2[k * 32 + c]);
    }
}

// ---------------- GEMM1 via MFMA: h1 = bf16(x) @ bf16(W1), out bf16 ----------------
// BM=128 BN=64 BK=32, 256 thr (4 waves), each wave -> 64x32 via 4x2 of 16x16x32 MFMAs.

__global__ __launch_bounds__(256) void k_gemm1m(const float* __restrict__ X, const unsigned short* __restrict__ WT,
                                                unsigned short* __restrict__ H) {
    __shared__ unsigned short As[128][40];
    __shared__ unsigned short Bs[64][40];
    int tid = threadIdx.x;
    int row0 = blockIdx.x * 128;
    int col0 = blockIdx.y * 64;
    int wv = tid >> 6, lane = tid & 63;
    int wm = wv & 1, wn = wv >> 1;
    int lr = lane & 15, quad = lane >> 4;
    f32x4 acc[4][2];
#pragma unroll
    for (int mt = 0; mt < 4; ++mt)
#pragma unroll
        for (int nt = 0; nt < 2; ++nt) acc[mt][nt] = (f32x4){0.f, 0.f, 0.f, 0.f};

    for (int k0 = 0; k0 < 256; k0 += 32) {
#pragma unroll
        for (int pass = 0; pass < 2; ++pass) {
            int u = tid + pass * 256;
            int r = u >> 2, seg = u & 3;
            int grow = row0 + r;
            float4 f0 = make_float4(0.f, 0.f, 0.f, 0.f), f1 = f0;
            if (grow < N_NODES) {
                const float* src = X + (size_t)grow * 256 + k0 + seg * 8;
                f0 = *(const float4*)src;
                f1 = *(const float4*)(src + 4);
            }
            *(uint4*)&As[r][seg * 8] = pack_bf16_trunc(f0, f1);
        }
        {
            int n = tid >> 2, seg = tid & 3;
            uint4 v = *(const uint4*)(WT + ((col0 + n) << 8) + k0 + seg * 8);
            *(uint4*)&Bs[n][seg * 8] = v;
        }
        __syncthreads();
        s16x8 a[4], b[2];
#pragma unroll
        for (int mt = 0; mt < 4; ++mt) a[mt] = *(const s16x8*)&As[wm * 64 + mt * 16 + lr][quad * 8];
#pragma unroll
        for (int nt = 0; nt < 2; ++nt) b[nt] = *(const s16x8*)&Bs[wn * 32 + nt * 16 + lr][quad * 8];
#pragma unroll
        for (int mt = 0; mt < 4; ++mt)
#pragma unroll
            for (int nt = 0; nt < 2; ++nt)
                acc[mt][nt] = __builtin_amdgcn_mfma_f32_16x16x32_bf16(a[mt], b[nt], acc[mt][nt], 0, 0, 0);
        __syncthreads();
    }
    // C/D layout: col = lane&15, row = quad*4 + reg
#pragma unroll
    for (int mt = 0; mt < 4; ++mt) {
#pragma unroll
        for (int r = 0; r < 4; ++r) {
            int row = row0 + wm * 64 + mt * 16 + quad * 4 + r;
            if (row < N_NODES) {
#pragma unroll
                for (int nt = 0; nt < 2; ++nt)
                    H[(size_t)row * 256 + col0 + wn * 32 + nt * 16 + lr] = f2bf(acc[mt][nt][r]);
            }
        }
    }
}

// ---------------- Layer-1 attention logits: 2 nodes per wave, 16B/lane loads ----------------

__global__ __launch_bounds__(256) void k_logits1(const unsigned short* __restrict__ H,
                                                 const float* __restrict__ a_src,
                                                 const float* __restrict__ a_dst, float* __restrict__ als,
                                                 float* __restrict__ ald) {
    int wid = (blockIdx.x * 256 + threadIdx.x) >> 6;
    int lane = threadIdx.x & 63;
    int sub = lane >> 5, sl = lane & 31;       // node half, channel group (8 ch per lane)
    int node = wid * 2 + sub;
    if (node >= N_NODES) return;
    uint4 hv = *(const uint4*)(H + (size_t)node * 256 + sl * 8);
    const unsigned* hp = (const unsigned*)&hv;
    float ps = 0.f, pd = 0.f;
#pragma unroll
    for (int t = 0; t < 4; ++t) {
        int c = sl * 8 + t * 2;
        float hlo = asf(hp[t] << 16), hhi = asf(hp[t] & 0xffff0000u);
        float2 av = *(const float2*)(a_src + c);
        float2 dv = *(const float2*)(a_dst + c);
        ps = fmaf(hhi, av.y, fmaf(hlo, av.x, ps));
        pd = fmaf(hhi, dv.y, fmaf(hlo, dv.x, pd));
    }
#pragma unroll
    for (int m = 4; m >= 1; m >>= 1) { ps += __shfl_xor(ps, m); pd += __shfl_xor(pd, m); }
    if ((sl & 7) == 0) {
        als[node * 4 + (sl >> 3)] = ps;
        ald[node * 4 + (sl >> 3)] = pd;
    }
}

// ---------------- Fused: layer-1 aggregation + bias + ELU + GEMM2 + layer-2 logits ----------------
// 4 waves/block, one node per wave, unroll-4 gather. Epilogue: W2^T bf16 in LDS (stride
// 264 -> b128 start-groups spread 8-ways), h2 row bf16 (broadcast reads) -> 32 b128
// LDS reads/wave instead of 256 scalar reads (round-4 bottleneck). LDS 18.9KB -> 8 blk/CU.

__global__ __launch_bounds__(256) void k_agg1g2(const unsigned short* __restrict__ H1,
                                                const float* __restrict__ als, const float* __restrict__ ald_,
                                                const int* __restrict__ off, const int* __restrict__ esrc,
                                                const float* __restrict__ b1, const unsigned short* __restrict__ W2T,
                                                const float* __restrict__ as2, const float* __restrict__ ad2,
                                                unsigned short* __restrict__ Gb, float* __restrict__ als2,
                                                float* __restrict__ ald2) {
    __shared__ __align__(16) unsigned short WsT[32][264];  // [col][k], stride 528B = 33x16B
    __shared__ __align__(16) unsigned short h2b[4][256];   // bf16 h2 row per wave
    int tid = threadIdx.x;
#pragma unroll
    for (int pass = 0; pass < 4; ++pass) {                 // 1024 16B-chunks
        int q = tid + pass * 256;
        int r = q >> 5, ch = q & 31;
        uint4 v = *(const uint4*)(W2T + r * 256 + ch * 8);
        *(uint4*)&WsT[r][ch * 8] = v;
    }
    int wv = tid >> 6, lane = tid & 63;
    int node = blockIdx.x * 4 + wv;   // 12500*4 == 50000, no bounds check
    int head = lane >> 4;
    float ald = ald_[node * 4 + head];
    int pstart = off[node], pend = off[node + 1];
    float l = 0.f, ax = 0.f, ay = 0.f, az = 0.f, aw = 0.f;
    const ushort4* H4 = (const ushort4*)H1;
    int p = pstart;
    for (; p + 3 < pend; p += 4) {
        int u0 = esrc[p], u1 = esrc[p + 1], u2 = esrc[p + 2], u3 = esrc[p + 3];
        ushort4 h0 = H4[(size_t)u0 * 64 + lane];
        ushort4 h1v = H4[(size_t)u1 * 64 + lane];
        ushort4 h2v = H4[(size_t)u2 * 64 + lane];
        ushort4 h3v = H4[(size_t)u3 * 64 + lane];
        float e0 = als[u0 * 4 + head] + ald;
        float e1 = als[u1 * 4 + head] + ald;
        float e2 = als[u2 * 4 + head] + ald;
        float e3 = als[u3 * 4 + head] + ald;
        e0 = e0 > 0.f ? e0 : NEG_SLOPE * e0;
        e1 = e1 > 0.f ? e1 : NEG_SLOPE * e1;
        e2 = e2 > 0.f ? e2 : NEG_SLOPE * e2;
        e3 = e3 > 0.f ? e3 : NEG_SLOPE * e3;
        float pw0 = __expf(e0), pw1 = __expf(e1), pw2 = __expf(e2), pw3 = __expf(e3);
        l += (pw0 + pw1) + (pw2 + pw3);
        ax = fmaf(pw3, bf2f(h3v.x), fmaf(pw2, bf2f(h2v.x), fmaf(pw1, bf2f(h1v.x), fmaf(pw0, bf2f(h0.x), ax))));
        ay = fmaf(pw3, bf2f(h3v.y), fmaf(pw2, bf2f(h2v.y), fmaf(pw1, bf2f(h1v.y), fmaf(pw0, bf2f(h0.y), ay))));
        az = fmaf(pw3, bf2f(h3v.z), fmaf(pw2, bf2f(h2v.z), fmaf(pw1, bf2f(h1v.z), fmaf(pw0, bf2f(h0.z), az))));
        aw = fmaf(pw3, bf2f(h3v.w), fmaf(pw2, bf2f(h2v.w), fmaf(pw1, bf2f(h1v.w), fmaf(pw0, bf2f(h0.w), aw))));
    }
    for (; p < pend; ++p) {
        int u0 = esrc[p];
        ushort4 h0 = H4[(size_t)u0 * 64 + lane];
        float e0 = als[u0 * 4 + head] + ald;
        e0 = e0 > 0.f ? e0 : NEG_SLOPE * e0;
        float pw0 = __expf(e0);
        l += pw0;
        ax = fmaf(pw0, bf2f(h0.x), ax);
        ay = fmaf(pw0, bf2f(h0.y), ay);
        az = fmaf(pw0, bf2f(h0.z), az);
        aw = fmaf(pw0, bf2f(h0.w), aw);
    }
    float inv = 1.f / l;
    int c = lane * 4;
    float4 bb = *(const float4*)(b1 + c);
    float o0 = ax * inv + bb.x, o1 = ay * inv + bb.y, o2 = az * inv + bb.z, o3 = aw * inv + bb.w;
    o0 = o0 > 0.f ? o0 : expm1f(o0);
    o1 = o1 > 0.f ? o1 : expm1f(o1);
    o2 = o2 > 0.f ? o2 : expm1f(o2);
    o3 = o3 > 0.f ? o3 : expm1f(o3);
    ushort4 hb;
    hb.x = f2bf(o0); hb.y = f2bf(o1); hb.z = f2bf(o2); hb.w = f2bf(o3);
    *(ushort4*)&h2b[wv][c] = hb;
    __syncthreads();   // covers WsT staging + h2b writes
    int col = lane & 31, half = lane >> 5, j0 = half * 128;
    float sum = 0.f;
#pragma unroll
    for (int jj = 0; jj < 16; ++jj) {
        int j = j0 + jj * 8;
        uint4 w4 = *(const uint4*)&WsT[col][j];
        uint4 h4 = *(const uint4*)&h2b[wv][j];
        const unsigned* wp = (const unsigned*)&w4;
        const unsigned* hp = (const unsigned*)&h4;
#pragma unroll
        for (int t = 0; t < 4; ++t) {
            float wlo = asf(wp[t] << 16), whi = asf(wp[t] & 0xffff0000u);
            float hlo = asf(hp[t] << 16), hhi = asf(hp[t] & 0xffff0000u);
            sum = fmaf(hlo, wlo, sum);
            sum = fmaf(hhi, whi, sum);
        }
    }
    float g = sum + __shfl_xor(sum, 32);
    if (half == 0) Gb[(size_t)node * 32 + col] = f2bf(g);
    float ps = g * as2[col];
    float pd = g * ad2[col];
#pragma unroll
    for (int msk = 16; msk >= 1; msk >>= 1) { ps += __shfl_xor(ps, msk); pd += __shfl_xor(pd, msk); }
    if (lane == 0) { als2[node] = ps; ald2[node] = pd; }
}

// ---------------- Layer-2 aggregation + bias + log_softmax (bf16 G, unroll-4) ----------------

__global__ __launch_bounds__(256) void k_agg2(const unsigned short* __restrict__ Gb,
                                              const float* __restrict__ als2,
                                              const float* __restrict__ ald2_, const int* __restrict__ off,
                                              const int* __restrict__ esrc, const float* __restrict__ b2,
                                              float* __restrict__ out) {
    int gid = blockIdx.x * 256 + threadIdx.x;
    int node = gid >> 5;
    int col = gid & 31;
    if (node >= N_NODES) return;
    float ald = ald2_[node];
    int pstart = off[node], pend = off[node + 1];
    float l = 0.f, acc = 0.f;
    int p = pstart;
    for (; p + 3 < pend; p += 4) {
        int u0 = esrc[p], u1 = esrc[p + 1], u2 = esrc[p + 2], u3 = esrc[p + 3];
        float g0 = bf2f(Gb[(size_t)u0 * 32 + col]);
        float g1 = bf2f(Gb[(size_t)u1 * 32 + col]);
        float g2 = bf2f(Gb[(size_t)u2 * 32 + col]);
        float g3 = bf2f(Gb[(size_t)u3 * 32 + col]);
        float e0 = als2[u0] + ald;
        float e1 = als2[u1] + ald;
        float e2 = als2[u2] + ald;
        float e3 = als2[u3] + ald;
        e0 = e0 > 0.f ? e0 : NEG_SLOPE * e0;
        e1 = e1 > 0.f ? e1 : NEG_SLOPE * e1;
        e2 = e2 > 0.f ? e2 : NEG_SLOPE * e2;
        e3 = e3 > 0.f ? e3 : NEG_SLOPE * e3;
        float pw0 = __expf(e0), pw1 = __expf(e1), pw2 = __expf(e2), pw3 = __expf(e3);
        l += (pw0 + pw1) + (pw2 + pw3);
        acc = fmaf(pw3, g3, fmaf(pw2, g2, fmaf(pw1, g1, fmaf(pw0, g0, acc))));
    }
    for (; p < pend; ++p) {
        int u0 = esrc[p];
        float g0 = bf2f(Gb[(size_t)u0 * 32 + col]);
        float e0 = als2[u0] + ald;
        e0 = e0 > 0.f ? e0 : NEG_SLOPE * e0;
        float pw0 = __expf(e0);
        l += pw0;
        acc = fmaf(pw0, g0, acc);
    }
    float o = acc / l + b2[col];
    float mm = o;
#pragma unroll
    for (int msk = 16; msk >= 1; msk >>= 1) mm = fmaxf(mm, __shfl_xor(mm, msk));
    float ex = __expf(o - mm);
    float s = ex;
#pragma unroll
    for (int msk = 16; msk >= 1; msk >>= 1) s += __shfl_xor(s, msk);
    out[(size_t)node * 32 + col] = o - mm - logf(s);
}

// ---------------- launch ----------------

extern "C" void kernel_launch(void* const* d_in, const int* in_sizes, int n_in,
                              void* d_out, int out_size, void* d_ws, size_t ws_size,
                              hipStream_t stream) {
    const float* x   = (const float*)d_in[0];
    const int*   ei  = (const int*)d_in[1];
    const float* W1  = (const float*)d_in[2];
    const float* as1 = (const float*)d_in[3];
    const float* ad1 = (const float*)d_in[4];
    const float* b1  = (const float*)d_in[5];
    const float* W2  = (const float*)d_in[6];
    const float* as2 = (const float*)d_in[7];
    const float* ad2 = (const float*)d_in[8];
    const float* b2  = (const float*)d_in[9];
    float* out = (float*)d_out;

    char* p = (char*)d_ws;
    auto alloc = [&](size_t bytes) {
        char* r = p;
        p += (bytes + 255) & ~(size_t)255;
        return r;
    };
    // workspace ~35 MB total (ws overflow corrupts harness state — keep small)
    unsigned short* h1  = (unsigned short*)alloc((size_t)N_NODES * 256 * 2);  // 25.6 MB bf16
    unsigned short* wt  = (unsigned short*)alloc((size_t)256 * 256 * 2);      // 128 KB bf16 W1^T
    unsigned short* w2t = (unsigned short*)alloc((size_t)32 * 256 * 2);       // 16 KB bf16 W2^T
    unsigned short* g   = (unsigned short*)alloc((size_t)N_NODES * 32 * 2);   // 3.2 MB bf16
    float* als1 = (float*)alloc((size_t)N_NODES * 4 * 4);
    float* ald1 = (float*)alloc((size_t)N_NODES * 4 * 4);
    float* als2 = (float*)alloc((size_t)N_NODES * 4);
    float* ald2 = (float*)alloc((size_t)N_NODES * 4);
    int* degcur = (int*)alloc((size_t)N_NODES * 2 * 4);   // deg | cur, one memset
    int* deg = degcur;
    int* cur = degcur + N_NODES;
    int* off  = (int*)alloc((size_t)(N_NODES + 1) * 4);
    int* bsum = (int*)alloc(64 * 4);
    int* boff = (int*)alloc(64 * 4);
    int* esrc = (int*)alloc((size_t)ET * 4);                                  // 3.4 MB

    hipMemsetAsync(degcur, 0, (size_t)N_NODES * 2 * 4, stream);

    k_hist<<<(ET + 255) / 256, 256, 0, stream>>>(ei, deg);
    k_scan_reduce<<<SCAN_NB, 256, 0, stream>>>(deg, bsum);
    k_scan_top<<<1, 64, 0, stream>>>(bsum, boff);
    k_scan_chunk<<<SCAN_NB, 256, 0, stream>>>(deg, boff, off);
    k_scatter<<<(ET + 255) / 256, 256, 0, stream>>>(ei, off, cur, esrc);

    k_cvtw<<<288, 256, 0, stream>>>(W1, W2, wt, w2t);
    k_gemm1m<<<dim3((N_NODES + 127) / 128, 4), 256, 0, stream>>>(x, wt, h1);
    k_logits1<<<(N_NODES / 2 + 3) / 4, 256, 0, stream>>>(h1, as1, ad1, als1, ald1);
    k_agg1g2<<<N_NODES / 4, 256, 0, stream>>>(h1, als1, ald1, off, esrc, b1, w2t, as2, ad2,
                                              g, als2, ald2);
    k_agg2<<<(N_NODES + 7) / 8, 256, 0, stream>>>(g, als2, ald2, off, esrc, b2, out);
}

// Round 6
// 310.368 us; speedup vs baseline: 1.8192x; 1.0748x over previous
//
#include <hip/hip_runtime.h>
#include <math.h>

#define N_NODES 50000
#define N_EDGES 800000
#define ET (N_EDGES + N_NODES)   // edges + self loops
#define NEG_SLOPE 0.2f

#define SCAN_CHUNK 1024
#define SCAN_NB ((N_NODES + SCAN_CHUNK - 1) / SCAN_CHUNK)  // 49

typedef __attribute__((ext_vector_type(8))) short s16x8;
typedef __attribute__((ext_vector_type(4))) float f32x4;
typedef __attribute__((ext_vector_type(2))) float f32x2;

__device__ __forceinline__ unsigned short f2bf(float f) {
    union { float f; unsigned u; } v; v.f = f;
    unsigned r = v.u + 0x7FFF + ((v.u >> 16) & 1);  // RNE
    return (unsigned short)(r >> 16);
}
__device__ __forceinline__ float bf2f(unsigned short s) {
    union { unsigned u; float f; } v; v.u = ((unsigned)s) << 16;
    return v.f;
}
__device__ __forceinline__ float asf(unsigned u) {
    union { unsigned u; float f; } v; v.u = u;
    return v.f;
}
// truncation-pack 8 fp32 -> 8 bf16
__device__ __forceinline__ uint4 pack_bf16_trunc(float4 f0, float4 f1) {
    const unsigned* a = (const unsigned*)&f0;
    const unsigned* b = (const unsigned*)&f1;
    uint4 r;
    r.x = (a[0] >> 16) | (a[1] & 0xffff0000u);
    r.y = (a[2] >> 16) | (a[3] & 0xffff0000u);
    r.z = (b[0] >> 16) | (b[1] & 0xffff0000u);
    r.w = (b[2] >> 16) | (b[3] & 0xffff0000u);
    return r;
}
// fp8 e4m3 (OCP) helpers — HW converts
__device__ __forceinline__ unsigned char f2fp8(float f) {
    return (unsigned char)(__builtin_amdgcn_cvt_pk_fp8_f32(f, f, 0, false) & 0xff);
}

// ---------------- CSR build ----------------

__global__ __launch_bounds__(256) void k_hist(const int* __restrict__ ei, int* __restrict__ deg) {
    int e = blockIdx.x * 256 + threadIdx.x;
    if (e >= ET) return;
    int v = (e < N_EDGES) ? ei[N_EDGES + e] : (e - N_EDGES);
    if (v >= 0 && v < N_NODES) atomicAdd(&deg[v], 1);
}

__global__ __launch_bounds__(256) void k_scan_reduce(const int* __restrict__ deg, int* __restrict__ bsum) {
    __shared__ int red[256];
    int b = blockIdx.x, tid = threadIdx.x;
    int s = 0;
    for (int i = tid; i < SCAN_CHUNK; i += 256) {
        int idx = b * SCAN_CHUNK + i;
        if (idx < N_NODES) s += deg[idx];
    }
    red[tid] = s;
    __syncthreads();
    for (int st = 128; st > 0; st >>= 1) {
        if (tid < st) red[tid] += red[tid + st];
        __syncthreads();
    }
    if (tid == 0) bsum[b] = red[0];
}

__global__ __launch_bounds__(64) void k_scan_top(const int* __restrict__ bsum, int* __restrict__ boff) {
    int lane = threadIdx.x;
    int v = (lane < SCAN_NB) ? bsum[lane] : 0;
    int incl = v;
    for (int o = 1; o < 64; o <<= 1) {
        int t = __shfl_up(incl, o);
        if (lane >= o) incl += t;
    }
    boff[lane] = incl - v;
}

__global__ __launch_bounds__(256) void k_scan_chunk(const int* __restrict__ deg, const int* __restrict__ boff,
                                                   int* __restrict__ off) {
    __shared__ int wsum[4];
    int b = blockIdx.x, tid = threadIdx.x;
    int lane = tid & 63, wid = tid >> 6;
    int base = b * SCAN_CHUNK + tid * 4;
    int d[4];
#pragma unroll
    for (int j = 0; j < 4; ++j) d[j] = (base + j < N_NODES) ? deg[base + j] : 0;
    int tsum = d[0] + d[1] + d[2] + d[3];
    int incl = tsum;
    for (int o = 1; o < 64; o <<= 1) {
        int t = __shfl_up(incl, o);
        if (lane >= o) incl += t;
    }
    int wexcl = incl - tsum;
    if (lane == 63) wsum[wid] = incl;
    __syncthreads();
    int wbase = 0;
    for (int w = 0; w < wid; ++w) wbase += wsum[w];
    int run = boff[b] + wbase + wexcl;
#pragma unroll
    for (int j = 0; j < 4; ++j) {
        if (base + j < N_NODES) off[base + j] = run;
        run += d[j];
    }
    if (b == 0 && tid == 0) off[N_NODES] = ET;
}

__global__ __launch_bounds__(256) void k_scatter(const int* __restrict__ ei, const int* __restrict__ off,
                                                 int* __restrict__ cur, int* __restrict__ esrc) {
    int e = blockIdx.x * 256 + threadIdx.x;
    if (e >= ET) return;
    int u, v;
    if (e < N_EDGES) { u = ei[e]; v = ei[N_EDGES + e]; } else { u = e - N_EDGES; v = u; }
    if (v < 0 || v >= N_NODES) return;
    int p = off[v] + atomicAdd(&cur[v], 1);
    esrc[p] = u;
}

// ---------------- weight converts: W1 -> bf16 W1^T [256][256]; W2 -> bf16 W2^T [32][256] ----------------

__global__ __launch_bounds__(256) void k_cvtw(const float* __restrict__ W1, const float* __restrict__ W2,
                                              unsigned short* __restrict__ WT, unsigned short* __restrict__ W2T) {
    int b = blockIdx.x, k = threadIdx.x;
    if (b < 256) {
        WT[b * 256 + k] = f2bf(W1[k * 256 + b]);
    } else {
        int c = b - 256;
        W2T[c * 256 + k] = f2bf(W2[k * 32 + c]);
    }
}

// ---------------- GEMM1 via MFMA: h1 = bf16(x) @ bf16(W1), out fp8 e4m3 ----------------
// BM=64, BN=256 (all cols in-kernel -> X read ONCE), BK=32. 256 thr = 4 waves (2x2),
// each wave 32x128 via 2x8 of 16x16x32 MFMAs. LDS ~25KB.

__global__ __launch_bounds__(256) void k_gemm1m(const float* __restrict__ X, const unsigned short* __restrict__ WT,
                                                unsigned char* __restrict__ H8) {
    __shared__ unsigned short As[64][40];
    __shared__ unsigned short Bs[256][40];
    int tid = threadIdx.x;
    int row0 = blockIdx.x * 64;
    int wv = tid >> 6, lane = tid & 63;
    int wm = wv & 1, wn = wv >> 1;
    int lr = lane & 15, quad = lane >> 4;
    f32x4 acc[2][8];
#pragma unroll
    for (int mt = 0; mt < 2; ++mt)
#pragma unroll
        for (int nt = 0; nt < 8; ++nt) acc[mt][nt] = (f32x4){0.f, 0.f, 0.f, 0.f};

    int ar = tid >> 2, aseg = tid & 3;
    for (int k0 = 0; k0 < 256; k0 += 32) {
        {   // A: 64 rows x 32 k, fp32->bf16 on the fly
            int grow = row0 + ar;
            float4 f0 = make_float4(0.f, 0.f, 0.f, 0.f), f1 = f0;
            if (grow < N_NODES) {
                const float* src = X + (size_t)grow * 256 + k0 + aseg * 8;
                f0 = *(const float4*)src;
                f1 = *(const float4*)(src + 4);
            }
            *(uint4*)&As[ar][aseg * 8] = pack_bf16_trunc(f0, f1);
        }
#pragma unroll
        for (int pass = 0; pass < 4; ++pass) {   // B: 256 n x 32 k  (1024 16B chunks)
            int q = tid + pass * 256;
            int n = q >> 2, seg = q & 3;
            uint4 v = *(const uint4*)(WT + (n << 8) + k0 + seg * 8);
            *(uint4*)&Bs[n][seg * 8] = v;
        }
        __syncthreads();
        s16x8 a[2], b[8];
#pragma unroll
        for (int mt = 0; mt < 2; ++mt) a[mt] = *(const s16x8*)&As[wm * 32 + mt * 16 + lr][quad * 8];
#pragma unroll
        for (int nt = 0; nt < 8; ++nt) b[nt] = *(const s16x8*)&Bs[wn * 128 + nt * 16 + lr][quad * 8];
#pragma unroll
        for (int mt = 0; mt < 2; ++mt)
#pragma unroll
            for (int nt = 0; nt < 8; ++nt)
                acc[mt][nt] = __builtin_amdgcn_mfma_f32_16x16x32_bf16(a[mt], b[nt], acc[mt][nt], 0, 0, 0);
        __syncthreads();
    }
    // C/D layout: col = lane&15, row = quad*4 + reg
#pragma unroll
    for (int mt = 0; mt < 2; ++mt) {
#pragma unroll
        for (int r = 0; r < 4; ++r) {
            int row = row0 + wm * 32 + mt * 16 + quad * 4 + r;
            if (row < N_NODES) {
#pragma unroll
                for (int nt = 0; nt < 8; ++nt) {
                    int col = wn * 128 + nt * 16 + lr;
                    H8[(size_t)row * 256 + col] = f2fp8(acc[mt][nt][r]);
                }
            }
        }
    }
}

// ---------------- Layer-1 attention logits (reads fp8 h1) ----------------
// one wave per node; lane owns 4 channels (one dword); head = lane>>4.

__global__ __launch_bounds__(256) void k_logits1(const unsigned* __restrict__ H8u,
                                                 const float* __restrict__ a_src,
                                                 const float* __restrict__ a_dst, float* __restrict__ als,
                                                 float* __restrict__ ald) {
    int wid = (blockIdx.x * 256 + threadIdx.x) >> 6;
    int lane = threadIdx.x & 63;
    if (wid >= N_NODES) return;
    unsigned hv = H8u[(size_t)wid * 64 + lane];
    f32x2 p0 = __builtin_amdgcn_cvt_pk_f32_fp8(hv, false);
    f32x2 p1 = __builtin_amdgcn_cvt_pk_f32_fp8(hv, true);
    float4 as = *(const float4*)(a_src + lane * 4);
    float4 ad = *(const float4*)(a_dst + lane * 4);
    float ps = p0.x * as.x + p0.y * as.y + p1.x * as.z + p1.y * as.w;
    float pd = p0.x * ad.x + p0.y * ad.y + p1.x * ad.z + p1.y * ad.w;
#pragma unroll
    for (int m = 8; m >= 1; m >>= 1) { ps += __shfl_xor(ps, m); pd += __shfl_xor(pd, m); }
    if ((lane & 15) == 0) {
        als[wid * 4 + (lane >> 4)] = ps;
        ald[wid * 4 + (lane >> 4)] = pd;
    }
}

// ---------------- Fused: layer-1 aggregation + bias + ELU + GEMM2 + layer-2 logits ----------------
// 4 waves/block, one node per wave, unroll-4. Gather payload fp8 (4 B/lane, 256 B/edge):
// FETCH compulsory floor = 8 XCD x 12.8 MB ~ 105 MB (was 206 with bf16 — the round-5 wall).

__global__ __launch_bounds__(256) void k_agg1g2(const unsigned* __restrict__ H8u,
                                                const float* __restrict__ als, const float* __restrict__ ald_,
                                                const int* __restrict__ off, const int* __restrict__ esrc,
                                                const float* __restrict__ b1, const unsigned short* __restrict__ W2T,
                                                const float* __restrict__ as2, const float* __restrict__ ad2,
                                                unsigned short* __restrict__ Gb, float* __restrict__ als2,
                                                float* __restrict__ ald2) {
    __shared__ __align__(16) unsigned short WsT[32][264];  // [col][k] bf16, stride 528B
    __shared__ __align__(16) unsigned short h2b[4][256];   // bf16 h2 row per wave
    int tid = threadIdx.x;
#pragma unroll
    for (int pass = 0; pass < 4; ++pass) {
        int q = tid + pass * 256;
        int r = q >> 5, ch = q & 31;
        uint4 v = *(const uint4*)(W2T + r * 256 + ch * 8);
        *(uint4*)&WsT[r][ch * 8] = v;
    }
    int wv = tid >> 6, lane = tid & 63;
    int node = blockIdx.x * 4 + wv;   // 12500*4 == 50000
    int head = lane >> 4;
    float ald = ald_[node * 4 + head];
    int pstart = off[node], pend = off[node + 1];
    float l = 0.f, ax = 0.f, ay = 0.f, az = 0.f, aw = 0.f;
    int p = pstart;
    for (; p + 3 < pend; p += 4) {
        int u0 = esrc[p], u1 = esrc[p + 1], u2 = esrc[p + 2], u3 = esrc[p + 3];
        unsigned v0 = H8u[(size_t)u0 * 64 + lane];
        unsigned v1 = H8u[(size_t)u1 * 64 + lane];
        unsigned v2 = H8u[(size_t)u2 * 64 + lane];
        unsigned v3 = H8u[(size_t)u3 * 64 + lane];
        float e0 = als[u0 * 4 + head] + ald;
        float e1 = als[u1 * 4 + head] + ald;
        float e2 = als[u2 * 4 + head] + ald;
        float e3 = als[u3 * 4 + head] + ald;
        e0 = e0 > 0.f ? e0 : NEG_SLOPE * e0;
        e1 = e1 > 0.f ? e1 : NEG_SLOPE * e1;
        e2 = e2 > 0.f ? e2 : NEG_SLOPE * e2;
        e3 = e3 > 0.f ? e3 : NEG_SLOPE * e3;
        float pw0 = __expf(e0), pw1 = __expf(e1), pw2 = __expf(e2), pw3 = __expf(e3);
        l += (pw0 + pw1) + (pw2 + pw3);
        f32x2 a0 = __builtin_amdgcn_cvt_pk_f32_fp8(v0, false), b0 = __builtin_amdgcn_cvt_pk_f32_fp8(v0, true);
        f32x2 a1 = __builtin_amdgcn_cvt_pk_f32_fp8(v1, false), b1v = __builtin_amdgcn_cvt_pk_f32_fp8(v1, true);
        f32x2 a2 = __builtin_amdgcn_cvt_pk_f32_fp8(v2, false), b2v = __builtin_amdgcn_cvt_pk_f32_fp8(v2, true);
        f32x2 a3 = __builtin_amdgcn_cvt_pk_f32_fp8(v3, false), b3v = __builtin_amdgcn_cvt_pk_f32_fp8(v3, true);
        ax = fmaf(pw3, a3.x, fmaf(pw2, a2.x, fmaf(pw1, a1.x, fmaf(pw0, a0.x, ax))));
        ay = fmaf(pw3, a3.y, fmaf(pw2, a2.y, fmaf(pw1, a1.y, fmaf(pw0, a0.y, ay))));
        az = fmaf(pw3, b3v.x, fmaf(pw2, b2v.x, fmaf(pw1, b1v.x, fmaf(pw0, b0.x, az))));
        aw = fmaf(pw3, b3v.y, fmaf(pw2, b2v.y, fmaf(pw1, b1v.y, fmaf(pw0, b0.y, aw))));
    }
    for (; p < pend; ++p) {
        int u0 = esrc[p];
        unsigned v0 = H8u[(size_t)u0 * 64 + lane];
        float e0 = als[u0 * 4 + head] + ald;
        e0 = e0 > 0.f ? e0 : NEG_SLOPE * e0;
        float pw0 = __expf(e0);
        l += pw0;
        f32x2 a0 = __builtin_amdgcn_cvt_pk_f32_fp8(v0, false), b0 = __builtin_amdgcn_cvt_pk_f32_fp8(v0, true);
        ax = fmaf(pw0, a0.x, ax);
        ay = fmaf(pw0, a0.y, ay);
        az = fmaf(pw0, b0.x, az);
        aw = fmaf(pw0, b0.y, aw);
    }
    float inv = 1.f / l;
    int c = lane * 4;
    float4 bb = *(const float4*)(b1 + c);
    float o0 = ax * inv + bb.x, o1 = ay * inv + bb.y, o2 = az * inv + bb.z, o3 = aw * inv + bb.w;
    o0 = o0 > 0.f ? o0 : expm1f(o0);
    o1 = o1 > 0.f ? o1 : expm1f(o1);
    o2 = o2 > 0.f ? o2 : expm1f(o2);
    o3 = o3 > 0.f ? o3 : expm1f(o3);
    ushort4 hb;
    hb.x = f2bf(o0); hb.y = f2bf(o1); hb.z = f2bf(o2); hb.w = f2bf(o3);
    *(ushort4*)&h2b[wv][c] = hb;
    __syncthreads();   // covers WsT staging + h2b writes
    int col = lane & 31, half = lane >> 5, j0 = half * 128;
    float sum = 0.f;
#pragma unroll
    for (int jj = 0; jj < 16; ++jj) {
        int j = j0 + jj * 8;
        uint4 w4 = *(const uint4*)&WsT[col][j];
        uint4 h4 = *(const uint4*)&h2b[wv][j];
        const unsigned* wp = (const unsigned*)&w4;
        const unsigned* hp = (const unsigned*)&h4;
#pragma unroll
        for (int t = 0; t < 4; ++t) {
            float wlo = asf(wp[t] << 16), whi = asf(wp[t] & 0xffff0000u);
            float hlo = asf(hp[t] << 16), hhi = asf(hp[t] & 0xffff0000u);
            sum = fmaf(hlo, wlo, sum);
            sum = fmaf(hhi, whi, sum);
        }
    }
    float g = sum + __shfl_xor(sum, 32);
    if (half == 0) Gb[(size_t)node * 32 + col] = f2bf(g);
    float ps = g * as2[col];
    float pd = g * ad2[col];
#pragma unroll
    for (int msk = 16; msk >= 1; msk >>= 1) { ps += __shfl_xor(ps, msk); pd += __shfl_xor(pd, msk); }
    if (lane == 0) { als2[node] = ps; ald2[node] = pd; }
}

// ---------------- Layer-2 aggregation + bias + log_softmax (bf16 G, unroll-4) ----------------

__global__ __launch_bounds__(256) void k_agg2(const unsigned short* __restrict__ Gb,
                                              const float* __restrict__ als2,
                                              const float* __restrict__ ald2_, const int* __restrict__ off,
                                              const int* __restrict__ esrc, const float* __restrict__ b2,
                                              float* __restrict__ out) {
    int gid = blockIdx.x * 256 + threadIdx.x;
    int node = gid >> 5;
    int col = gid & 31;
    if (node >= N_NODES) return;
    float ald = ald2_[node];
    int pstart = off[node], pend = off[node + 1];
    float l = 0.f, acc = 0.f;
    int p = pstart;
    for (; p + 3 < pend; p += 4) {
        int u0 = esrc[p], u1 = esrc[p + 1], u2 = esrc[p + 2], u3 = esrc[p + 3];
        float g0 = bf2f(Gb[(size_t)u0 * 32 + col]);
        float g1 = bf2f(Gb[(size_t)u1 * 32 + col]);
        float g2 = bf2f(Gb[(size_t)u2 * 32 + col]);
        float g3 = bf2f(Gb[(size_t)u3 * 32 + col]);
        float e0 = als2[u0] + ald;
        float e1 = als2[u1] + ald;
        float e2 = als2[u2] + ald;
        float e3 = als2[u3] + ald;
        e0 = e0 > 0.f ? e0 : NEG_SLOPE * e0;
        e1 = e1 > 0.f ? e1 : NEG_SLOPE * e1;
        e2 = e2 > 0.f ? e2 : NEG_SLOPE * e2;
        e3 = e3 > 0.f ? e3 : NEG_SLOPE * e3;
        float pw0 = __expf(e0), pw1 = __expf(e1), pw2 = __expf(e2), pw3 = __expf(e3);
        l += (pw0 + pw1) + (pw2 + pw3);
        acc = fmaf(pw3, g3, fmaf(pw2, g2, fmaf(pw1, g1, fmaf(pw0, g0, acc))));
    }
    for (; p < pend; ++p) {
        int u0 = esrc[p];
        float g0 = bf2f(Gb[(size_t)u0 * 32 + col]);
        float e0 = als2[u0] + ald;
        e0 = e0 > 0.f ? e0 : NEG_SLOPE * e0;
        float pw0 = __expf(e0);
        l += pw0;
        acc = fmaf(pw0, g0, acc);
    }
    float o = acc / l + b2[col];
    float mm = o;
#pragma unroll
    for (int msk = 16; msk >= 1; msk >>= 1) mm = fmaxf(mm, __shfl_xor(mm, msk));
    float ex = __expf(o - mm);
    float s = ex;
#pragma unroll
    for (int msk = 16; msk >= 1; msk >>= 1) s += __shfl_xor(s, msk);
    out[(size_t)node * 32 + col] = o - mm - logf(s);
}

// ---------------- launch ----------------

extern "C" void kernel_launch(void* const* d_in, const int* in_sizes, int n_in,
                              void* d_out, int out_size, void* d_ws, size_t ws_size,
                              hipStream_t stream) {
    const float* x   = (const float*)d_in[0];
    const int*   ei  = (const int*)d_in[1];
    const float* W1  = (const float*)d_in[2];
    const float* as1 = (const float*)d_in[3];
    const float* ad1 = (const float*)d_in[4];
    const float* b1  = (const float*)d_in[5];
    const float* W2  = (const float*)d_in[6];
    const float* as2 = (const float*)d_in[7];
    const float* ad2 = (const float*)d_in[8];
    const float* b2  = (const float*)d_in[9];
    float* out = (float*)d_out;

    char* p = (char*)d_ws;
    auto alloc = [&](size_t bytes) {
        char* r = p;
        p += (bytes + 255) & ~(size_t)255;
        return r;
    };
    // workspace ~22 MB total (well under the known-good 38 MB)
    unsigned char*  h8  = (unsigned char*)alloc((size_t)N_NODES * 256);       // 12.8 MB fp8
    unsigned short* wt  = (unsigned short*)alloc((size_t)256 * 256 * 2);      // 128 KB bf16 W1^T
    unsigned short* w2t = (unsigned short*)alloc((size_t)32 * 256 * 2);       // 16 KB bf16 W2^T
    unsigned short* g   = (unsigned short*)alloc((size_t)N_NODES * 32 * 2);   // 3.2 MB bf16
    float* als1 = (float*)alloc((size_t)N_NODES * 4 * 4);
    float* ald1 = (float*)alloc((size_t)N_NODES * 4 * 4);
    float* als2 = (float*)alloc((size_t)N_NODES * 4);
    float* ald2 = (float*)alloc((size_t)N_NODES * 4);
    int* degcur = (int*)alloc((size_t)N_NODES * 2 * 4);
    int* deg = degcur;
    int* cur = degcur + N_NODES;
    int* off  = (int*)alloc((size_t)(N_NODES + 1) * 4);
    int* bsum = (int*)alloc(64 * 4);
    int* boff = (int*)alloc(64 * 4);
    int* esrc = (int*)alloc((size_t)ET * 4);                                  // 3.4 MB

    hipMemsetAsync(degcur, 0, (size_t)N_NODES * 2 * 4, stream);

    k_hist<<<(ET + 255) / 256, 256, 0, stream>>>(ei, deg);
    k_scan_reduce<<<SCAN_NB, 256, 0, stream>>>(deg, bsum);
    k_scan_top<<<1, 64, 0, stream>>>(bsum, boff);
    k_scan_chunk<<<SCAN_NB, 256, 0, stream>>>(deg, boff, off);
    k_scatter<<<(ET + 255) / 256, 256, 0, stream>>>(ei, off, cur, esrc);

    k_cvtw<<<288, 256, 0, stream>>>(W1, W2, wt, w2t);
    k_gemm1m<<<(N_NODES + 63) / 64, 256, 0, stream>>>(x, wt, h8);
    k_logits1<<<(N_NODES + 3) / 4, 256, 0, stream>>>((const unsigned*)h8, as1, ad1, als1, ald1);
    k_agg1g2<<<N_NODES / 4, 256, 0, stream>>>((const unsigned*)h8, als1, ald1, off, esrc, b1, w2t,
                                              as2, ad2, g, als2, ald2);
    k_agg2<<<(N_NODES + 7) / 8, 256, 0, stream>>>(g, als2, ald2, off, esrc, b2, out);
}